// Round 1
// baseline (619.297 us; speedup 1.0000x reference)
//
#include <hip/hip_runtime.h>
#include <math.h>

#define NN 16384
#define EE 262144
#define FF 32
#define HH 128
#define BB 16
#define DI 256
#define DS 16
#define DC 4
#define DTR 8
#define OUTW 1552
#define NCH 128
#define CHLEN 128   // NCH*CHLEN == NN

// ---------------------------------------------------------------- utilities
__device__ __forceinline__ float siluf(float v) { return v / (1.f + __expf(-v)); }
__device__ __forceinline__ float softplusf(float v) {
    return fmaxf(v, 0.f) + log1pf(expf(-fabsf(v)));
}

// ---------------------------------------------------------------- CSR build
__global__ void deg_kernel(const int* __restrict__ dst, int* __restrict__ cnt) {
    int e = blockIdx.x * blockDim.x + threadIdx.x;
    if (e < EE) atomicAdd(&cnt[dst[e]], 1);
}

// one block, 256 threads; 64 nodes per thread
__global__ void prefix_kernel(const int* __restrict__ cnt, int* __restrict__ rowptr,
                              int* __restrict__ cursor, float* __restrict__ dinv) {
    __shared__ int part[256];
    int tid = threadIdx.x;
    int s = 0;
    for (int i = 0; i < 64; i++) s += cnt[tid * 64 + i];
    part[tid] = s;
    __syncthreads();
    for (int off = 1; off < 256; off <<= 1) {
        int v = 0;
        if (tid >= off) v = part[tid - off];
        __syncthreads();
        part[tid] += v;
        __syncthreads();
    }
    int running = part[tid] - s;  // exclusive start of this thread's chunk
    for (int i = 0; i < 64; i++) {
        int idx = tid * 64 + i;
        int c = cnt[idx];
        rowptr[idx] = running;
        cursor[idx] = running;
        dinv[idx] = rsqrtf((float)(c + 1));  // +1 self loop
        running += c;
    }
    if (tid == 255) rowptr[NN] = part[255];
}

__global__ void scatter_kernel(const int* __restrict__ src, const int* __restrict__ dst,
                               int* __restrict__ cursor, int* __restrict__ col) {
    int e = blockIdx.x * blockDim.x + threadIdx.x;
    if (e < EE) {
        int d = dst[e];
        int pos = atomicAdd(&cursor[d], 1);
        col[pos] = src[e];
    }
}

// ---------------------------------------------------------------- GEMM (fp32, 64x64 tile)
// act: 0 none, 1 relu
__global__ __launch_bounds__(256) void gemm_k(const float* __restrict__ A,
                                              const float* __restrict__ B,
                                              const float* __restrict__ bias,
                                              float* __restrict__ C,
                                              int M, int Nn, int K, int act) {
    __shared__ float As[16][65];
    __shared__ float Bs[16][65];
    int tid = threadIdx.x;
    int m0 = blockIdx.y * 64;
    int n0 = blockIdx.x * 64;
    int ty = tid >> 4, tx = tid & 15;
    float acc[4][4] = {{0.f}};
    for (int k0 = 0; k0 < K; k0 += 16) {
#pragma unroll
        for (int l = 0; l < 4; l++) {
            int idx = tid + l * 256;
            int i = idx >> 4, j = idx & 15;
            As[j][i] = A[(size_t)(m0 + i) * K + k0 + j];
        }
#pragma unroll
        for (int l = 0; l < 4; l++) {
            int idx = tid + l * 256;
            int i = idx >> 6, j = idx & 63;
            int n = n0 + j;
            Bs[i][j] = (n < Nn) ? B[(size_t)(k0 + i) * Nn + n] : 0.f;
        }
        __syncthreads();
#pragma unroll
        for (int kk = 0; kk < 16; kk++) {
            float a[4], b[4];
#pragma unroll
            for (int r = 0; r < 4; r++) a[r] = As[kk][ty + r * 16];
#pragma unroll
            for (int c = 0; c < 4; c++) b[c] = Bs[kk][tx + c * 16];
#pragma unroll
            for (int r = 0; r < 4; r++)
#pragma unroll
                for (int c = 0; c < 4; c++) acc[r][c] = fmaf(a[r], b[c], acc[r][c]);
        }
        __syncthreads();
    }
#pragma unroll
    for (int r = 0; r < 4; r++) {
        int m = m0 + ty + r * 16;
#pragma unroll
        for (int c = 0; c < 4; c++) {
            int n = n0 + tx + c * 16;
            if (n < Nn) {
                float v = acc[r][c];
                if (bias) v += bias[n];
                if (act == 1) v = fmaxf(v, 0.f);
                C[(size_t)m * Nn + n] = v;
            }
        }
    }
}

// ---------------------------------------------------------------- GCN gather (CSR by dest)
__global__ void gcn_gather(const float* __restrict__ xw, const int* __restrict__ rowptr,
                           const int* __restrict__ col, const float* __restrict__ dinv,
                           const float* __restrict__ b, float* __restrict__ out) {
    int n = blockIdx.x;
    int f = threadIdx.x;  // 128
    float dn = dinv[n];
    float acc = xw[(size_t)n * HH + f] * dn * dn;  // self loop
    int beg = rowptr[n], end = rowptr[n + 1];
    for (int e = beg; e < end; e++) {
        int sn = col[e];
        acc += xw[(size_t)sn * HH + f] * (dinv[sn] * dn);
    }
    acc += b[f];
    out[(size_t)n * HH + f] = fmaxf(acc, 0.f);
}

// ---------------------------------------------------------------- causal depthwise conv + silu
__global__ void conv_silu(const float* __restrict__ xz, const float* __restrict__ cw,
                          const float* __restrict__ cb, float* __restrict__ xs) {
    int idx = blockIdx.x * blockDim.x + threadIdx.x;
    int t = idx >> 8, d = idx & 255;
    float acc = cb[d];
#pragma unroll
    for (int k = 0; k < DC; k++) {
        int tt = t + k - (DC - 1);
        if (tt >= 0) acc = fmaf(xz[(size_t)tt * 512 + d], cw[d * DC + k], acc);
    }
    xs[(size_t)t * DI + d] = siluf(acc);
}

// ---------------------------------------------------------------- dt projection + softplus
__global__ void dt_kernel(const float* __restrict__ dbl, const float* __restrict__ W_dt,
                          const float* __restrict__ b_dt, float* __restrict__ dt) {
    int idx = blockIdx.x * blockDim.x + threadIdx.x;
    int t = idx >> 8, d = idx & 255;
    float acc = b_dt[d];
#pragma unroll
    for (int j = 0; j < DTR; j++) acc = fmaf(dbl[(size_t)t * 40 + j], W_dt[j * DI + d], acc);
    dt[(size_t)t * DI + d] = softplusf(acc);
}

// ---------------------------------------------------------------- Mamba scan, 3 phases
// lane layout: s = lane&15, d_local = wave*4 + (lane>>4); block covers 16 d; grid (16, NCH)
__global__ __launch_bounds__(256) void scan_phase1(const float* __restrict__ dt,
                                                   const float* __restrict__ xs,
                                                   const float* __restrict__ dbl,
                                                   const float* __restrict__ A_log,
                                                   float* __restrict__ chkP,
                                                   float* __restrict__ chkH) {
    int dblk = blockIdx.x, chunk = blockIdx.y;
    int tid = threadIdx.x;
    int wave = tid >> 6, lane = tid & 63;
    int s = lane & 15;
    int d = dblk * 16 + (wave << 2) + (lane >> 4);
    float A_v = -expf(A_log[d * DS + s]);
    float h = 0.f, P = 1.f;
    int t0 = chunk * CHLEN;
    for (int i = 0; i < CHLEN; i++) {
        int t = t0 + i;
        float dtv = dt[(size_t)t * DI + d];
        float a = __expf(dtv * A_v);
        float bv = dtv * dbl[(size_t)t * 40 + 8 + s] * xs[(size_t)t * DI + d];
        h = fmaf(a, h, bv);
        P *= a;
    }
    int idx = chunk * 4096 + d * DS + s;
    chkP[idx] = P;
    chkH[idx] = h;
}

__global__ void scan_phase2(const float* __restrict__ chkP, const float* __restrict__ chkH,
                            float* __restrict__ init) {
    int idx = blockIdx.x * blockDim.x + threadIdx.x;  // 4096 total
    float h = 0.f;
    for (int c = 0; c < NCH; c++) {
        init[c * 4096 + idx] = h;
        h = fmaf(chkP[c * 4096 + idx], h, chkH[c * 4096 + idx]);
    }
}

__global__ __launch_bounds__(256) void scan_phase3(const float* __restrict__ dt,
                                                   const float* __restrict__ xs,
                                                   const float* __restrict__ dbl,
                                                   const float* __restrict__ A_log,
                                                   const float* __restrict__ init,
                                                   const float* __restrict__ D_p,
                                                   const float* __restrict__ xz,
                                                   float* __restrict__ yb) {
    int dblk = blockIdx.x, chunk = blockIdx.y;
    int tid = threadIdx.x;
    int wave = tid >> 6, lane = tid & 63;
    int s = lane & 15;
    int d = dblk * 16 + (wave << 2) + (lane >> 4);
    float A_v = -expf(A_log[d * DS + s]);
    float Dd = D_p[d];
    float h = init[chunk * 4096 + d * DS + s];
    int t0 = chunk * CHLEN;
    for (int i = 0; i < CHLEN; i++) {
        int t = t0 + i;
        float dtv = dt[(size_t)t * DI + d];
        float a = __expf(dtv * A_v);
        float xv = xs[(size_t)t * DI + d];
        float bv = dtv * dbl[(size_t)t * 40 + 8 + s] * xv;
        h = fmaf(a, h, bv);
        float c = h * dbl[(size_t)t * 40 + 24 + s];
        c += __shfl_xor(c, 1);
        c += __shfl_xor(c, 2);
        c += __shfl_xor(c, 4);
        c += __shfl_xor(c, 8);
        if (s == 0) {
            float zv = xz[(size_t)t * 512 + DI + d];
            // NOTE: yb aliases xs; this lane already read xs[t*DI+d] above (same lane, program order)
            yb[(size_t)t * DI + d] = (c + Dd * xv) * siluf(zv);
        }
    }
}

// ---------------------------------------------------------------- add + LayerNorm (wave per row)
__global__ void add_ln(const float* __restrict__ hg, const float* __restrict__ hm,
                       const float* __restrict__ gamma, const float* __restrict__ beta,
                       float* __restrict__ out) {
    int row = blockIdx.x * 4 + (threadIdx.x >> 6);
    int lane = threadIdx.x & 63;
    size_t base = (size_t)row * HH;
    float v0 = hg[base + lane] + hm[base + lane];
    float v1 = hg[base + 64 + lane] + hm[base + 64 + lane];
    float sum = v0 + v1;
#pragma unroll
    for (int m = 32; m >= 1; m >>= 1) sum += __shfl_xor(sum, m);
    float mu = sum * (1.f / 128.f);
    float d0 = v0 - mu, d1 = v1 - mu;
    float vs = d0 * d0 + d1 * d1;
#pragma unroll
    for (int m = 32; m >= 1; m >>= 1) vs += __shfl_xor(vs, m);
    float inv = rsqrtf(vs * (1.f / 128.f) + 1e-5f);
    out[base + lane] = d0 * inv * gamma[lane] + beta[lane];
    out[base + 64 + lane] = d1 * inv * gamma[64 + lane] + beta[64 + lane];
}

// ---------------------------------------------------------------- pooling (batch sorted)
__global__ void pool_kernel(const float* __restrict__ hf, const int* __restrict__ batch,
                            float* __restrict__ ge, int* __restrict__ counts) {
    int f = threadIdx.x;  // 128
    int r0 = blockIdx.x * 128;
    int gcur = batch[r0];
    float acc = 0.f;
    int cnt = 0;
    for (int i = 0; i < 128; i++) {
        int r = r0 + i;
        int g = batch[r];
        if (g != gcur) {
            atomicAdd(&ge[gcur * HH + f], acc);
            if (f == 0) atomicAdd(&counts[gcur], cnt);
            acc = 0.f; cnt = 0; gcur = g;
        }
        acc += hf[(size_t)r * HH + f];
        cnt++;
    }
    atomicAdd(&ge[gcur * HH + f], acc);
    if (f == 0) atomicAdd(&counts[gcur], cnt);
}

__global__ void ge_norm(float* __restrict__ ge, const int* __restrict__ counts) {
    int idx = blockIdx.x * blockDim.x + threadIdx.x;
    if (idx < BB * HH) {
        int b = idx >> 7;
        ge[idx] /= fmaxf((float)counts[b], 1.f);
    }
}

// ---------------------------------------------------------------- output heads
__global__ void heads_kernel(const float* __restrict__ ge,
                             const float* Wc, const float* bc, const float* Wh, const float* bh,
                             const float* Wt, const float* bt, const float* Wp1, const float* bp1,
                             const float* Wp2, const float* bp2, const float* Wd, const float* bd,
                             const float* Ws, const float* bs, float* __restrict__ out) {
    int col = blockIdx.x * blockDim.x + threadIdx.x;
    int b = blockIdx.y;
    if (col >= OUTW) return;
    const float* W; const float* bi; int lc, w;
    if (col < 1)         { W = Wc;  bi = bc;  lc = col;        w = 1; }
    else if (col < 5)    { W = Wh;  bi = bh;  lc = col - 1;    w = 4; }
    else if (col < 8)    { W = Wt;  bi = bt;  lc = col - 5;    w = 3; }
    else if (col < 520)  { W = Wp1; bi = bp1; lc = col - 8;    w = 512; }
    else if (col < 1032) { W = Wp2; bi = bp2; lc = col - 520;  w = 512; }
    else if (col < 1544) { W = Wd;  bi = bd;  lc = col - 1032; w = 512; }
    else                 { W = Ws;  bi = bs;  lc = col - 1544; w = 8; }
    float acc = bi[lc];
#pragma unroll 8
    for (int f = 0; f < HH; f++) acc = fmaf(ge[b * HH + f], W[f * w + lc], acc);
    out[(size_t)b * OUTW + col] = acc;
}

// ---------------------------------------------------------------- launch
extern "C" void kernel_launch(void* const* d_in, const int* in_sizes, int n_in,
                              void* d_out, int out_size, void* d_ws, size_t ws_size,
                              hipStream_t stream) {
    const float* nf      = (const float*)d_in[0];
    const int*   ei      = (const int*)d_in[1];
    const int*   batch   = (const int*)d_in[2];
    const float* W_in    = (const float*)d_in[3];
    const float* b_in    = (const float*)d_in[4];
    const float* W_g1    = (const float*)d_in[5];
    const float* b_g1    = (const float*)d_in[6];
    const float* W_g2    = (const float*)d_in[7];
    const float* b_g2    = (const float*)d_in[8];
    const float* W_inproj= (const float*)d_in[9];
    const float* conv_w  = (const float*)d_in[10];
    const float* conv_b  = (const float*)d_in[11];
    const float* W_xproj = (const float*)d_in[12];
    const float* W_dt    = (const float*)d_in[13];
    const float* b_dt    = (const float*)d_in[14];
    const float* A_log   = (const float*)d_in[15];
    const float* D_p     = (const float*)d_in[16];
    const float* W_out   = (const float*)d_in[17];
    const float* gamma   = (const float*)d_in[18];
    const float* beta    = (const float*)d_in[19];
    const float* Wc = (const float*)d_in[20]; const float* bc = (const float*)d_in[21];
    const float* Wh = (const float*)d_in[22]; const float* bh = (const float*)d_in[23];
    const float* Wt = (const float*)d_in[24]; const float* bt = (const float*)d_in[25];
    const float* Wp1= (const float*)d_in[26]; const float* bp1= (const float*)d_in[27];
    const float* Wp2= (const float*)d_in[28]; const float* bp2= (const float*)d_in[29];
    const float* Wd = (const float*)d_in[30]; const float* bd = (const float*)d_in[31];
    const float* Ws = (const float*)d_in[32]; const float* bs = (const float*)d_in[33];

    const int* e_src = ei;
    const int* e_dst = ei + EE;

    // workspace layout (floats, then ints)
    float* w = (float*)d_ws;
    size_t o = 0;
    float* F0   = w + o; o += (size_t)NN * HH;
    float* F1   = w + o; o += (size_t)NN * HH;
    float* F2   = w + o; o += (size_t)NN * HH;
    float* XZ   = w + o; o += (size_t)NN * 512;
    float* XS   = w + o; o += (size_t)NN * DI;   // conv output; later aliased as yb
    float* DBL  = w + o; o += (size_t)NN * 40;
    float* DT   = w + o; o += (size_t)NN * DI;
    float* CHP  = w + o; o += (size_t)NCH * 4096;
    float* CHH  = w + o; o += (size_t)NCH * 4096;
    float* INI  = w + o; o += (size_t)NCH * 4096;
    float* GE   = w + o; o += BB * HH;
    float* DINV = w + o; o += NN;
    int* ip = (int*)(w + o);
    int* CNT    = ip; ip += NN;
    int* ROWPTR = ip; ip += NN + 1;
    int* CURSOR = ip; ip += NN;
    int* COL    = ip; ip += EE;
    int* COUNTS = ip; ip += BB;

    hipMemsetAsync(CNT, 0, NN * sizeof(int), stream);
    hipMemsetAsync(GE, 0, BB * HH * sizeof(float), stream);
    hipMemsetAsync(COUNTS, 0, BB * sizeof(int), stream);

    // CSR build
    deg_kernel<<<EE / 256, 256, 0, stream>>>(e_dst, CNT);
    prefix_kernel<<<1, 256, 0, stream>>>(CNT, ROWPTR, CURSOR, DINV);
    scatter_kernel<<<EE / 256, 256, 0, stream>>>(e_src, e_dst, CURSOR, COL);

    // h0 = relu(nf @ W_in + b_in)
    gemm_k<<<dim3(2, NN / 64), 256, 0, stream>>>(nf, W_in, b_in, F0, NN, HH, FF, 1);
    // GCN layer 1
    gemm_k<<<dim3(2, NN / 64), 256, 0, stream>>>(F0, W_g1, nullptr, F1, NN, HH, HH, 0);
    gcn_gather<<<NN, HH, 0, stream>>>(F1, ROWPTR, COL, DINV, b_g1, F0);
    // GCN layer 2
    gemm_k<<<dim3(2, NN / 64), 256, 0, stream>>>(F0, W_g2, nullptr, F1, NN, HH, HH, 0);
    gcn_gather<<<NN, HH, 0, stream>>>(F1, ROWPTR, COL, DINV, b_g2, F2);  // F2 = h_gnn

    // xz = h_gnn @ W_inproj
    gemm_k<<<dim3(8, NN / 64), 256, 0, stream>>>(F2, W_inproj, nullptr, XZ, NN, 512, HH, 0);
    // conv + silu
    conv_silu<<<NN * DI / 256, 256, 0, stream>>>(XZ, conv_w, conv_b, XS);
    // dbl = xs @ W_xproj
    gemm_k<<<dim3(1, NN / 64), 256, 0, stream>>>(XS, W_xproj, nullptr, DBL, NN, 40, DI, 0);
    // dt
    dt_kernel<<<NN * DI / 256, 256, 0, stream>>>(DBL, W_dt, b_dt, DT);

    // Mamba scan
    scan_phase1<<<dim3(DI / 16, NCH), 256, 0, stream>>>(DT, XS, DBL, A_log, CHP, CHH);
    scan_phase2<<<16, 256, 0, stream>>>(CHP, CHH, INI);
    scan_phase3<<<dim3(DI / 16, NCH), 256, 0, stream>>>(DT, XS, DBL, A_log, INI, D_p, XZ, XS /*yb alias*/);

    // h_mamba = yb @ W_out -> F1
    gemm_k<<<dim3(2, NN / 64), 256, 0, stream>>>(XS, W_out, nullptr, F1, NN, HH, DI, 0);
    // hh = h_gnn + h_mamba; LayerNorm -> F0
    add_ln<<<NN / 4, 256, 0, stream>>>(F2, F1, gamma, beta, F0);

    // pooling
    pool_kernel<<<NN / 128, HH, 0, stream>>>(F0, batch, GE, COUNTS);
    ge_norm<<<(BB * HH + 255) / 256, 256, 0, stream>>>(GE, COUNTS);

    // heads
    heads_kernel<<<dim3((OUTW + 127) / 128, BB), 128, 0, stream>>>(
        GE, Wc, bc, Wh, bh, Wt, bt, Wp1, bp1, Wp2, bp2, Wd, bd, Ws, bs, (float*)d_out);
}

// Round 2
// 618.880 us; speedup vs baseline: 1.0007x; 1.0007x over previous
//
#include <hip/hip_runtime.h>
#include <math.h>

#define NN 16384
#define EE 262144
#define FF 32
#define HH 128
#define BB 16
#define DI 256
#define DS 16
#define DC 4
#define DTR 8
#define OUTW 1552
#define NCH 128
#define CHLEN 128   // NCH*CHLEN == NN

// ---------------------------------------------------------------- utilities
__device__ __forceinline__ float siluf(float v) { return v / (1.f + __expf(-v)); }
__device__ __forceinline__ float softplusf(float v) {
    return fmaxf(v, 0.f) + log1pf(expf(-fabsf(v)));
}

// ---------------------------------------------------------------- CSR build
__global__ void deg_kernel(const int* __restrict__ dst, int* __restrict__ cnt) {
    int e = blockIdx.x * blockDim.x + threadIdx.x;
    if (e < EE) atomicAdd(&cnt[dst[e]], 1);
}

// one block, 256 threads; 64 nodes per thread
__global__ void prefix_kernel(const int* __restrict__ cnt, int* __restrict__ rowptr,
                              int* __restrict__ cursor, float* __restrict__ dinv) {
    __shared__ int part[256];
    int tid = threadIdx.x;
    int s = 0;
    for (int i = 0; i < 64; i++) s += cnt[tid * 64 + i];
    part[tid] = s;
    __syncthreads();
    for (int off = 1; off < 256; off <<= 1) {
        int v = 0;
        if (tid >= off) v = part[tid - off];
        __syncthreads();
        part[tid] += v;
        __syncthreads();
    }
    int running = part[tid] - s;
    for (int i = 0; i < 64; i++) {
        int idx = tid * 64 + i;
        int c = cnt[idx];
        rowptr[idx] = running;
        cursor[idx] = running;
        dinv[idx] = rsqrtf((float)(c + 1));  // +1 self loop
        running += c;
    }
    if (tid == 255) rowptr[NN] = part[255];
}

__global__ void scatter_kernel(const int* __restrict__ src, const int* __restrict__ dst,
                               int* __restrict__ cursor, int* __restrict__ col) {
    int e = blockIdx.x * blockDim.x + threadIdx.x;
    if (e < EE) {
        int d = dst[e];
        int pos = atomicAdd(&cursor[d], 1);
        col[pos] = src[e];
    }
}

// ---------------------------------------------------------------- GEMM (fp32, 64x64 tile)
__global__ __launch_bounds__(256) void gemm_k(const float* __restrict__ A,
                                              const float* __restrict__ B,
                                              const float* __restrict__ bias,
                                              float* __restrict__ C,
                                              int M, int Nn, int K, int act) {
    __shared__ float As[16][65];
    __shared__ float Bs[16][65];
    int tid = threadIdx.x;
    int m0 = blockIdx.y * 64;
    int n0 = blockIdx.x * 64;
    int ty = tid >> 4, tx = tid & 15;
    float acc[4][4] = {{0.f}};
    for (int k0 = 0; k0 < K; k0 += 16) {
#pragma unroll
        for (int l = 0; l < 4; l++) {
            int idx = tid + l * 256;
            int i = idx >> 4, j = idx & 15;
            As[j][i] = A[(size_t)(m0 + i) * K + k0 + j];
        }
#pragma unroll
        for (int l = 0; l < 4; l++) {
            int idx = tid + l * 256;
            int i = idx >> 6, j = idx & 63;
            int n = n0 + j;
            Bs[i][j] = (n < Nn) ? B[(size_t)(k0 + i) * Nn + n] : 0.f;
        }
        __syncthreads();
#pragma unroll
        for (int kk = 0; kk < 16; kk++) {
            float a[4], b[4];
#pragma unroll
            for (int r = 0; r < 4; r++) a[r] = As[kk][ty + r * 16];
#pragma unroll
            for (int c = 0; c < 4; c++) b[c] = Bs[kk][tx + c * 16];
#pragma unroll
            for (int r = 0; r < 4; r++)
#pragma unroll
                for (int c = 0; c < 4; c++) acc[r][c] = fmaf(a[r], b[c], acc[r][c]);
        }
        __syncthreads();
    }
#pragma unroll
    for (int r = 0; r < 4; r++) {
        int m = m0 + ty + r * 16;
#pragma unroll
        for (int c = 0; c < 4; c++) {
            int n = n0 + tx + c * 16;
            if (n < Nn) {
                float v = acc[r][c];
                if (bias) v += bias[n];
                if (act == 1) v = fmaxf(v, 0.f);
                C[(size_t)m * Nn + n] = v;
            }
        }
    }
}

// ---------------------------------------------------------------- GEMM with A^T input (A stored [K][M])
__global__ __launch_bounds__(256) void gemm_at(const float* __restrict__ AT,
                                               const float* __restrict__ B,
                                               float* __restrict__ C,
                                               int M, int Nn, int K) {
    __shared__ float As[16][65];
    __shared__ float Bs[16][65];
    int tid = threadIdx.x;
    int m0 = blockIdx.y * 64;
    int n0 = blockIdx.x * 64;
    int ty = tid >> 4, tx = tid & 15;
    float acc[4][4] = {{0.f}};
    for (int k0 = 0; k0 < K; k0 += 16) {
#pragma unroll
        for (int l = 0; l < 4; l++) {
            int idx = tid + l * 256;
            int kk = idx >> 6, i = idx & 63;
            As[kk][i] = AT[(size_t)(k0 + kk) * M + m0 + i];  // coalesced along m
        }
#pragma unroll
        for (int l = 0; l < 4; l++) {
            int idx = tid + l * 256;
            int i = idx >> 6, j = idx & 63;
            int n = n0 + j;
            Bs[i][j] = (n < Nn) ? B[(size_t)(k0 + i) * Nn + n] : 0.f;
        }
        __syncthreads();
#pragma unroll
        for (int kk = 0; kk < 16; kk++) {
            float a[4], b[4];
#pragma unroll
            for (int r = 0; r < 4; r++) a[r] = As[kk][ty + r * 16];
#pragma unroll
            for (int c = 0; c < 4; c++) b[c] = Bs[kk][tx + c * 16];
#pragma unroll
            for (int r = 0; r < 4; r++)
#pragma unroll
                for (int c = 0; c < 4; c++) acc[r][c] = fmaf(a[r], b[c], acc[r][c]);
        }
        __syncthreads();
    }
#pragma unroll
    for (int r = 0; r < 4; r++) {
        int m = m0 + ty + r * 16;
#pragma unroll
        for (int c = 0; c < 4; c++) {
            int n = n0 + tx + c * 16;
            if (n < Nn) C[(size_t)m * Nn + n] = acc[r][c];
        }
    }
}

// ---------------------------------------------------------------- GCN gather (CSR by dest)
__global__ void gcn_gather(const float* __restrict__ xw, const int* __restrict__ rowptr,
                           const int* __restrict__ col, const float* __restrict__ dinv,
                           const float* __restrict__ b, float* __restrict__ out) {
    int n = blockIdx.x;
    int f = threadIdx.x;  // 128
    float dn = dinv[n];
    float acc = xw[(size_t)n * HH + f] * dn * dn;  // self loop
    int beg = rowptr[n], end = rowptr[n + 1];
    for (int e = beg; e < end; e++) {
        int sn = col[e];
        acc += xw[(size_t)sn * HH + f] * (dinv[sn] * dn);
    }
    acc += b[f];
    out[(size_t)n * HH + f] = fmaxf(acc, 0.f);
}

// ---------------------------------------------------------------- conv + silu, transposed outputs
// Tile: 64 t x 64 cols of xz[NN][512]. cols<256: causal conv+silu -> XS_T[d][t];
// cols>=256: silu -> SZ_T[d-256][t]. LDS transpose, padded.
__global__ __launch_bounds__(256) void conv_silu_t(const float* __restrict__ xz,
                                                   const float* __restrict__ cw,
                                                   const float* __restrict__ cb,
                                                   float* __restrict__ xst,
                                                   float* __restrict__ szt) {
    __shared__ float tile[67][65];
    int tid = threadIdx.x;
    int t0 = blockIdx.x * 64;
    int c0 = blockIdx.y * 64;
    // load rows t0-3 .. t0+63 (67 rows) x 64 cols, coalesced
#pragma unroll
    for (int l = 0; l < 17; l++) {
        int idx = tid + l * 256;
        if (idx < 67 * 64) {
            int r = idx >> 6, c = idx & 63;
            int gt = t0 - 3 + r;
            tile[r][c] = (gt >= 0) ? xz[(size_t)gt * 512 + c0 + c] : 0.f;
        }
    }
    __syncthreads();
    int tl = tid & 63;          // t within tile (lane-fast => coalesced writes)
    int d0 = tid >> 6;          // 0..3
    if (c0 < 256) {
#pragma unroll
        for (int l = 0; l < 16; l++) {
            int dl = d0 + l * 4;
            int dg = c0 + dl;
            float acc = cb[dg];
#pragma unroll
            for (int k = 0; k < DC; k++)
                acc = fmaf(tile[tl + k][dl], cw[dg * DC + k], acc);
            xst[dg * NN + t0 + tl] = siluf(acc);
        }
    } else {
#pragma unroll
        for (int l = 0; l < 16; l++) {
            int dl = d0 + l * 4;
            int dg = c0 - 256 + dl;
            szt[dg * NN + t0 + tl] = siluf(tile[tl + 3][dl]);
        }
    }
}

// ---------------------------------------------------------------- transpose dbl [NN][40] -> [40][NN]
__global__ __launch_bounds__(256) void transpose_dbl(const float* __restrict__ dbl,
                                                     float* __restrict__ dblt) {
    __shared__ float tile[64][41];
    int tid = threadIdx.x;
    int t0 = blockIdx.x * 64;
#pragma unroll
    for (int l = 0; l < 10; l++) {
        int idx = tid + l * 256;
        int r = idx / 40, c = idx - r * 40;
        tile[r][c] = dbl[(size_t)(t0 + r) * 40 + c];
    }
    __syncthreads();
#pragma unroll
    for (int l = 0; l < 10; l++) {
        int idx = tid + l * 256;
        int c = idx >> 6, t = idx & 63;
        dblt[c * NN + t0 + t] = tile[t][c];
    }
}

// ---------------------------------------------------------------- dt (transposed): DT_T[d][t]
__global__ __launch_bounds__(256) void dt_t_kernel(const float* __restrict__ dblt,
                                                   const float* __restrict__ W_dt,
                                                   const float* __restrict__ b_dt,
                                                   float* __restrict__ dtt) {
    int t = blockIdx.x * 256 + threadIdx.x;
    int d = blockIdx.y;
    float acc = b_dt[d];
#pragma unroll
    for (int j = 0; j < DTR; j++)
        acc = fmaf(dblt[j * NN + t], W_dt[j * DI + d], acc);
    dtt[d * NN + t] = softplusf(acc);
}

// ---------------------------------------------------------------- Mamba scan, 3 phases
// lane layout: s = lane&15, d_local = wave*4 + (lane>>4); block covers 16 d
__global__ __launch_bounds__(256) void scan_phase1(const float* __restrict__ dtt,
                                                   const float* __restrict__ xst,
                                                   const float* __restrict__ dblt,
                                                   const float* __restrict__ A_log,
                                                   float* __restrict__ chkP,
                                                   float* __restrict__ chkH) {
    int tid = threadIdx.x;
    int wave = tid >> 6, lane = tid & 63;
    int s = lane & 15;
    int d = blockIdx.x * 16 + (wave << 2) + (lane >> 4);
    int chunk = blockIdx.y;
    int t0 = chunk * CHLEN;
    float A_v = -expf(A_log[d * DS + s]);
    const float* dtp = dtt + d * NN + t0;
    const float* xsp = xst + d * NN + t0;
    const float* btp = dblt + (8 + s) * NN + t0;
    float h = 0.f, P = 1.f;
    for (int i = 0; i < CHLEN; i += 4) {
        float4 d4 = *(const float4*)(dtp + i);
        float4 x4 = *(const float4*)(xsp + i);
        float4 b4 = *(const float4*)(btp + i);
#define P1STEP(U) { float a = __expf(d4.U * A_v); h = fmaf(a, h, d4.U * b4.U * x4.U); P *= a; }
        P1STEP(x) P1STEP(y) P1STEP(z) P1STEP(w)
#undef P1STEP
    }
    int idx = chunk * 4096 + d * DS + s;
    chkP[idx] = P;
    chkH[idx] = h;
}

__global__ void scan_phase2(const float* __restrict__ chkP, const float* __restrict__ chkH,
                            float* __restrict__ init) {
    int idx = blockIdx.x * blockDim.x + threadIdx.x;  // 4096 total
    float h = 0.f;
    for (int c = 0; c < NCH - 1; c++) {
        init[c * 4096 + idx] = h;
        h = fmaf(chkP[c * 4096 + idx], h, chkH[c * 4096 + idx]);
    }
    init[(NCH - 1) * 4096 + idx] = h;
}

__global__ __launch_bounds__(256) void scan_phase3(const float* __restrict__ dtt,
                                                   const float* __restrict__ xst,
                                                   const float* __restrict__ dblt,
                                                   const float* __restrict__ A_log,
                                                   const float* __restrict__ init,
                                                   const float* __restrict__ D_p,
                                                   const float* __restrict__ szt,
                                                   float* __restrict__ y) {
    int tid = threadIdx.x;
    int wave = tid >> 6, lane = tid & 63;
    int s = lane & 15;
    int d = blockIdx.x * 16 + (wave << 2) + (lane >> 4);
    int chunk = blockIdx.y;
    int t0 = chunk * CHLEN;
    float A_v = -expf(A_log[d * DS + s]);
    float Dd = D_p[d];
    const float* dtp = dtt + d * NN + t0;
    const float* xsp = xst + d * NN + t0;
    const float* btp = dblt + (8 + s) * NN + t0;
    const float* ctp = dblt + (24 + s) * NN + t0;
    const float* szp = szt + d * NN + t0;
    float* yout = y + t0 * DI;
    float h = init[chunk * 4096 + d * DS + s];
    for (int i = 0; i < CHLEN; i += 4) {
        float4 d4 = *(const float4*)(dtp + i);
        float4 x4 = *(const float4*)(xsp + i);
        float4 b4 = *(const float4*)(btp + i);
        float4 c4 = *(const float4*)(ctp + i);
        float4 z4 = *(const float4*)(szp + i);
#define P3STEP(U) { \
        float a = __expf(d4.U * A_v); \
        h = fmaf(a, h, d4.U * b4.U * x4.U); \
        float c = h * c4.U; \
        c += __shfl_xor(c, 1); c += __shfl_xor(c, 2); \
        c += __shfl_xor(c, 4); c += __shfl_xor(c, 8); \
        if (s == 0) yout[d] = (c + Dd * x4.U) * z4.U; \
        yout += DI; }
        P3STEP(x) P3STEP(y) P3STEP(z) P3STEP(w)
#undef P3STEP
    }
}

// ---------------------------------------------------------------- add + LayerNorm (wave per row)
__global__ void add_ln(const float* __restrict__ hg, const float* __restrict__ hm,
                       const float* __restrict__ gamma, const float* __restrict__ beta,
                       float* __restrict__ out) {
    int row = blockIdx.x * 4 + (threadIdx.x >> 6);
    int lane = threadIdx.x & 63;
    size_t base = (size_t)row * HH;
    float v0 = hg[base + lane] + hm[base + lane];
    float v1 = hg[base + 64 + lane] + hm[base + 64 + lane];
    float sum = v0 + v1;
#pragma unroll
    for (int m = 32; m >= 1; m >>= 1) sum += __shfl_xor(sum, m);
    float mu = sum * (1.f / 128.f);
    float d0 = v0 - mu, d1 = v1 - mu;
    float vs = d0 * d0 + d1 * d1;
#pragma unroll
    for (int m = 32; m >= 1; m >>= 1) vs += __shfl_xor(vs, m);
    float inv = rsqrtf(vs * (1.f / 128.f) + 1e-5f);
    out[base + lane] = d0 * inv * gamma[lane] + beta[lane];
    out[base + 64 + lane] = d1 * inv * gamma[64 + lane] + beta[64 + lane];
}

// ---------------------------------------------------------------- pooling (batch sorted)
__global__ void pool_kernel(const float* __restrict__ hf, const int* __restrict__ batch,
                            float* __restrict__ ge, int* __restrict__ counts) {
    int f = threadIdx.x;  // 128
    int r0 = blockIdx.x * 128;
    int gcur = batch[r0];
    float acc = 0.f;
    int cnt = 0;
    for (int i = 0; i < 128; i++) {
        int r = r0 + i;
        int g = batch[r];
        if (g != gcur) {
            atomicAdd(&ge[gcur * HH + f], acc);
            if (f == 0) atomicAdd(&counts[gcur], cnt);
            acc = 0.f; cnt = 0; gcur = g;
        }
        acc += hf[(size_t)r * HH + f];
        cnt++;
    }
    atomicAdd(&ge[gcur * HH + f], acc);
    if (f == 0) atomicAdd(&counts[gcur], cnt);
}

__global__ void ge_norm(float* __restrict__ ge, const int* __restrict__ counts) {
    int idx = blockIdx.x * blockDim.x + threadIdx.x;
    if (idx < BB * HH) {
        int b = idx >> 7;
        ge[idx] /= fmaxf((float)counts[b], 1.f);
    }
}

// ---------------------------------------------------------------- output heads
__global__ void heads_kernel(const float* __restrict__ ge,
                             const float* Wc, const float* bc, const float* Wh, const float* bh,
                             const float* Wt, const float* bt, const float* Wp1, const float* bp1,
                             const float* Wp2, const float* bp2, const float* Wd, const float* bd,
                             const float* Ws, const float* bs, float* __restrict__ out) {
    int col = blockIdx.x * blockDim.x + threadIdx.x;
    int b = blockIdx.y;
    if (col >= OUTW) return;
    const float* W; const float* bi; int lc, w;
    if (col < 1)         { W = Wc;  bi = bc;  lc = col;        w = 1; }
    else if (col < 5)    { W = Wh;  bi = bh;  lc = col - 1;    w = 4; }
    else if (col < 8)    { W = Wt;  bi = bt;  lc = col - 5;    w = 3; }
    else if (col < 520)  { W = Wp1; bi = bp1; lc = col - 8;    w = 512; }
    else if (col < 1032) { W = Wp2; bi = bp2; lc = col - 520;  w = 512; }
    else if (col < 1544) { W = Wd;  bi = bd;  lc = col - 1032; w = 512; }
    else                 { W = Ws;  bi = bs;  lc = col - 1544; w = 8; }
    float acc = bi[lc];
#pragma unroll 8
    for (int f = 0; f < HH; f++) acc = fmaf(ge[b * HH + f], W[f * w + lc], acc);
    out[(size_t)b * OUTW + col] = acc;
}

// ---------------------------------------------------------------- launch
extern "C" void kernel_launch(void* const* d_in, const int* in_sizes, int n_in,
                              void* d_out, int out_size, void* d_ws, size_t ws_size,
                              hipStream_t stream) {
    const float* nf      = (const float*)d_in[0];
    const int*   ei      = (const int*)d_in[1];
    const int*   batch   = (const int*)d_in[2];
    const float* W_in    = (const float*)d_in[3];
    const float* b_in    = (const float*)d_in[4];
    const float* W_g1    = (const float*)d_in[5];
    const float* b_g1    = (const float*)d_in[6];
    const float* W_g2    = (const float*)d_in[7];
    const float* b_g2    = (const float*)d_in[8];
    const float* W_inproj= (const float*)d_in[9];
    const float* conv_w  = (const float*)d_in[10];
    const float* conv_b  = (const float*)d_in[11];
    const float* W_xproj = (const float*)d_in[12];
    const float* W_dt    = (const float*)d_in[13];
    const float* b_dt    = (const float*)d_in[14];
    const float* A_log   = (const float*)d_in[15];
    const float* D_p     = (const float*)d_in[16];
    const float* W_out   = (const float*)d_in[17];
    const float* gamma   = (const float*)d_in[18];
    const float* beta    = (const float*)d_in[19];
    const float* Wc = (const float*)d_in[20]; const float* bc = (const float*)d_in[21];
    const float* Wh = (const float*)d_in[22]; const float* bh = (const float*)d_in[23];
    const float* Wt = (const float*)d_in[24]; const float* bt = (const float*)d_in[25];
    const float* Wp1= (const float*)d_in[26]; const float* bp1= (const float*)d_in[27];
    const float* Wp2= (const float*)d_in[28]; const float* bp2= (const float*)d_in[29];
    const float* Wd = (const float*)d_in[30]; const float* bd = (const float*)d_in[31];
    const float* Ws = (const float*)d_in[32]; const float* bs = (const float*)d_in[33];

    const int* e_src = ei;
    const int* e_dst = ei + EE;

    // workspace layout (floats, then ints)
    float* w = (float*)d_ws;
    size_t o = 0;
    float* F0   = w + o; o += (size_t)NN * HH;
    float* F1   = w + o; o += (size_t)NN * HH;
    float* F2   = w + o; o += (size_t)NN * HH;
    float* XZ   = w + o; o += (size_t)NN * 512;  // dead after conv_silu_t; reused:
    float* DTT  = XZ;                             //   DT_T [DI][NN]
    float* Y    = XZ + (size_t)NN * DI;           //   y    [NN][DI]
    float* XST  = w + o; o += (size_t)NN * DI;   // x (conv+silu), transposed [DI][NN]
    float* SZT  = w + o; o += (size_t)NN * DI;   // silu(z), transposed [DI][NN]
    float* DBL  = w + o; o += (size_t)NN * 40;
    float* DBLT = w + o; o += (size_t)NN * 40;   // [40][NN]; rows 8..23 = B^T, 24..39 = C^T
    float* CHP  = w + o; o += (size_t)NCH * 4096;
    float* CHH  = w + o; o += (size_t)NCH * 4096;
    float* INI  = w + o; o += (size_t)NCH * 4096;
    float* GE   = w + o; o += BB * HH;
    float* DINV = w + o; o += NN;
    int* ip = (int*)(w + o);
    int* CNT    = ip; ip += NN;
    int* ROWPTR = ip; ip += NN + 1;
    int* CURSOR = ip; ip += NN;
    int* COL    = ip; ip += EE;
    int* COUNTS = ip; ip += BB;

    hipMemsetAsync(CNT, 0, NN * sizeof(int), stream);
    hipMemsetAsync(GE, 0, BB * HH * sizeof(float), stream);
    hipMemsetAsync(COUNTS, 0, BB * sizeof(int), stream);

    // CSR build
    deg_kernel<<<EE / 256, 256, 0, stream>>>(e_dst, CNT);
    prefix_kernel<<<1, 256, 0, stream>>>(CNT, ROWPTR, CURSOR, DINV);
    scatter_kernel<<<EE / 256, 256, 0, stream>>>(e_src, e_dst, CURSOR, COL);

    // h0 = relu(nf @ W_in + b_in)
    gemm_k<<<dim3(2, NN / 64), 256, 0, stream>>>(nf, W_in, b_in, F0, NN, HH, FF, 1);
    // GCN layer 1
    gemm_k<<<dim3(2, NN / 64), 256, 0, stream>>>(F0, W_g1, nullptr, F1, NN, HH, HH, 0);
    gcn_gather<<<NN, HH, 0, stream>>>(F1, ROWPTR, COL, DINV, b_g1, F0);
    // GCN layer 2
    gemm_k<<<dim3(2, NN / 64), 256, 0, stream>>>(F0, W_g2, nullptr, F1, NN, HH, HH, 0);
    gcn_gather<<<NN, HH, 0, stream>>>(F1, ROWPTR, COL, DINV, b_g2, F2);  // F2 = h_gnn

    // xz = h_gnn @ W_inproj
    gemm_k<<<dim3(8, NN / 64), 256, 0, stream>>>(F2, W_inproj, nullptr, XZ, NN, 512, HH, 0);
    // conv + silu -> XST; silu(z) -> SZT (both transposed)
    conv_silu_t<<<dim3(NN / 64, 8), 256, 0, stream>>>(XZ, conv_w, conv_b, XST, SZT);
    // dbl = xs @ W_xproj (A^T layout)
    gemm_at<<<dim3(1, NN / 64), 256, 0, stream>>>(XST, W_xproj, DBL, NN, 40, DI);
    // transpose dbl -> DBLT
    transpose_dbl<<<NN / 64, 256, 0, stream>>>(DBL, DBLT);
    // dt (transposed) — overwrites XZ region (dead)
    dt_t_kernel<<<dim3(NN / 256, DI), 256, 0, stream>>>(DBLT, W_dt, b_dt, DTT);

    // Mamba scan
    scan_phase1<<<dim3(DI / 16, NCH - 1), 256, 0, stream>>>(DTT, XST, DBLT, A_log, CHP, CHH);
    scan_phase2<<<16, 256, 0, stream>>>(CHP, CHH, INI);
    scan_phase3<<<dim3(DI / 16, NCH), 256, 0, stream>>>(DTT, XST, DBLT, A_log, INI, D_p, SZT, Y);

    // h_mamba = y @ W_out -> F1
    gemm_k<<<dim3(2, NN / 64), 256, 0, stream>>>(Y, W_out, nullptr, F1, NN, HH, DI, 0);
    // hh = h_gnn + h_mamba; LayerNorm -> F0
    add_ln<<<NN / 4, 256, 0, stream>>>(F2, F1, gamma, beta, F0);

    // pooling
    pool_kernel<<<NN / 128, HH, 0, stream>>>(F0, batch, GE, COUNTS);
    ge_norm<<<(BB * HH + 255) / 256, 256, 0, stream>>>(GE, COUNTS);

    // heads
    heads_kernel<<<dim3((OUTW + 127) / 128, BB), 128, 0, stream>>>(
        GE, Wc, bc, Wh, bh, Wt, bt, Wp1, bp1, Wp2, bp2, Wd, bd, Ws, bs, (float*)d_out);
}

// Round 3
// 534.096 us; speedup vs baseline: 1.1595x; 1.1587x over previous
//
#include <hip/hip_runtime.h>
#include <math.h>

#define NN 16384
#define EE 262144
#define FF 32
#define HH 128
#define BB 16
#define DI 256
#define DS 16
#define DC 4
#define DTR 8
#define OUTW 1552
#define NCH 128
#define CHLEN 128   // NCH*CHLEN == NN

// ---------------------------------------------------------------- utilities
__device__ __forceinline__ float siluf(float v) { return v / (1.f + __expf(-v)); }
__device__ __forceinline__ float softplusf(float v) {
    return fmaxf(v, 0.f) + log1pf(expf(-fabsf(v)));
}

// ---------------------------------------------------------------- CSR build
__global__ void deg_kernel(const int* __restrict__ dst, int* __restrict__ cnt) {
    int e = blockIdx.x * blockDim.x + threadIdx.x;
    if (e < EE) atomicAdd(&cnt[dst[e]], 1);
}

// one block, 1024 threads; 16 nodes per thread, int4 loads + LDS scan
__global__ __launch_bounds__(1024) void prefix_kernel(const int* __restrict__ cnt,
                                                      int* __restrict__ rowptr,
                                                      int* __restrict__ cursor,
                                                      float* __restrict__ dinv) {
    __shared__ int part[1024];
    int tid = threadIdx.x;
    int4 c4[4];
#pragma unroll
    for (int j = 0; j < 4; j++) c4[j] = ((const int4*)cnt)[tid * 4 + j];
    int v[16] = {c4[0].x, c4[0].y, c4[0].z, c4[0].w, c4[1].x, c4[1].y, c4[1].z, c4[1].w,
                 c4[2].x, c4[2].y, c4[2].z, c4[2].w, c4[3].x, c4[3].y, c4[3].z, c4[3].w};
    int s = 0;
#pragma unroll
    for (int j = 0; j < 16; j++) s += v[j];
    part[tid] = s;
    __syncthreads();
    for (int off = 1; off < 1024; off <<= 1) {
        int t = (tid >= off) ? part[tid - off] : 0;
        __syncthreads();
        part[tid] += t;
        __syncthreads();
    }
    int running = part[tid] - s;
    int rp[16];
    float dv[16];
#pragma unroll
    for (int j = 0; j < 16; j++) {
        rp[j] = running;
        running += v[j];
        dv[j] = rsqrtf((float)(v[j] + 1));  // +1 self loop
    }
#pragma unroll
    for (int j = 0; j < 4; j++) {
        int4 r4; r4.x = rp[j*4]; r4.y = rp[j*4+1]; r4.z = rp[j*4+2]; r4.w = rp[j*4+3];
        ((int4*)rowptr)[tid * 4 + j] = r4;
        ((int4*)cursor)[tid * 4 + j] = r4;
        float4 d4; d4.x = dv[j*4]; d4.y = dv[j*4+1]; d4.z = dv[j*4+2]; d4.w = dv[j*4+3];
        ((float4*)dinv)[tid * 4 + j] = d4;
    }
    if (tid == 1023) rowptr[NN] = part[1023];
}

__global__ void scatter_kernel(const int* __restrict__ src, const int* __restrict__ dst,
                               int* __restrict__ cursor, int* __restrict__ col) {
    int e = blockIdx.x * blockDim.x + threadIdx.x;
    if (e < EE) {
        int d = dst[e];
        int pos = atomicAdd(&cursor[d], 1);
        col[pos] = src[e];
    }
}

// ---------------------------------------------------------------- GEMM (fp32, 64x64 tile)
// thread owns 4 consecutive m x 4 consecutive n -> ds_read_b128 + float4 stores
__global__ __launch_bounds__(256) void gemm_k(const float* __restrict__ A,
                                              const float* __restrict__ B,
                                              const float* __restrict__ bias,
                                              float* __restrict__ C,
                                              int M, int Nn, int K, int act) {
    __shared__ float As[16][68];
    __shared__ float Bs[16][68];
    int tid = threadIdx.x;
    int m0 = blockIdx.y * 64;
    int n0 = blockIdx.x * 64;
    int ty = tid >> 4, tx = tid & 15;
    float acc[4][4] = {{0.f}};
    for (int k0 = 0; k0 < K; k0 += 16) {
#pragma unroll
        for (int l = 0; l < 4; l++) {
            int idx = tid + l * 256;
            int i = idx >> 4, j = idx & 15;
            As[j][i] = A[(size_t)(m0 + i) * K + k0 + j];
        }
#pragma unroll
        for (int l = 0; l < 4; l++) {
            int idx = tid + l * 256;
            int i = idx >> 6, j = idx & 63;
            int n = n0 + j;
            Bs[i][j] = (n < Nn) ? B[(size_t)(k0 + i) * Nn + n] : 0.f;
        }
        __syncthreads();
#pragma unroll
        for (int kk = 0; kk < 16; kk++) {
            float4 a4 = *(const float4*)&As[kk][ty * 4];
            float4 b4 = *(const float4*)&Bs[kk][tx * 4];
            float av[4] = {a4.x, a4.y, a4.z, a4.w};
            float bv[4] = {b4.x, b4.y, b4.z, b4.w};
#pragma unroll
            for (int r = 0; r < 4; r++)
#pragma unroll
                for (int c = 0; c < 4; c++) acc[r][c] = fmaf(av[r], bv[c], acc[r][c]);
        }
        __syncthreads();
    }
    int nb = n0 + tx * 4;
    if (nb < Nn) {
        float4 bi4 = {0.f, 0.f, 0.f, 0.f};
        if (bias) bi4 = *(const float4*)&bias[nb];
#pragma unroll
        for (int r = 0; r < 4; r++) {
            int m = m0 + ty * 4 + r;
            float4 v;
            v.x = acc[r][0] + bi4.x; v.y = acc[r][1] + bi4.y;
            v.z = acc[r][2] + bi4.z; v.w = acc[r][3] + bi4.w;
            if (act == 1) {
                v.x = fmaxf(v.x, 0.f); v.y = fmaxf(v.y, 0.f);
                v.z = fmaxf(v.z, 0.f); v.w = fmaxf(v.w, 0.f);
            }
            *(float4*)&C[(size_t)m * Nn + nb] = v;
        }
    }
}

// ---------------------------------------------------------------- GEMM with A^T input (A stored [K][M])
__global__ __launch_bounds__(256) void gemm_at(const float* __restrict__ AT,
                                               const float* __restrict__ B,
                                               float* __restrict__ C,
                                               int M, int Nn, int K) {
    __shared__ float As[16][68];
    __shared__ float Bs[16][68];
    int tid = threadIdx.x;
    int m0 = blockIdx.y * 64;
    int n0 = blockIdx.x * 64;
    int ty = tid >> 4, tx = tid & 15;
    float acc[4][4] = {{0.f}};
    for (int k0 = 0; k0 < K; k0 += 16) {
#pragma unroll
        for (int l = 0; l < 4; l++) {
            int idx = tid + l * 256;
            int kk = idx >> 6, i = idx & 63;
            As[kk][i] = AT[(size_t)(k0 + kk) * M + m0 + i];
        }
#pragma unroll
        for (int l = 0; l < 4; l++) {
            int idx = tid + l * 256;
            int i = idx >> 6, j = idx & 63;
            int n = n0 + j;
            Bs[i][j] = (n < Nn) ? B[(size_t)(k0 + i) * Nn + n] : 0.f;
        }
        __syncthreads();
#pragma unroll
        for (int kk = 0; kk < 16; kk++) {
            float4 a4 = *(const float4*)&As[kk][ty * 4];
            float4 b4 = *(const float4*)&Bs[kk][tx * 4];
            float av[4] = {a4.x, a4.y, a4.z, a4.w};
            float bv[4] = {b4.x, b4.y, b4.z, b4.w};
#pragma unroll
            for (int r = 0; r < 4; r++)
#pragma unroll
                for (int c = 0; c < 4; c++) acc[r][c] = fmaf(av[r], bv[c], acc[r][c]);
        }
        __syncthreads();
    }
    int nb = n0 + tx * 4;
    if (nb < Nn) {
#pragma unroll
        for (int r = 0; r < 4; r++) {
            int m = m0 + ty * 4 + r;
            float4 v;
            v.x = acc[r][0]; v.y = acc[r][1]; v.z = acc[r][2]; v.w = acc[r][3];
            *(float4*)&C[(size_t)m * Nn + nb] = v;
        }
    }
}

// ---------------------------------------------------------------- GCN gather (CSR by dest)
__global__ void gcn_gather(const float* __restrict__ xw, const int* __restrict__ rowptr,
                           const int* __restrict__ col, const float* __restrict__ dinv,
                           const float* __restrict__ b, float* __restrict__ out) {
    int n = blockIdx.x;
    int f = threadIdx.x;  // 128
    float dn = dinv[n];
    float acc = xw[(size_t)n * HH + f] * dn * dn;  // self loop
    int beg = rowptr[n], end = rowptr[n + 1];
    int e = beg;
    for (; e + 2 <= end; e += 2) {
        int s1 = col[e], s2 = col[e + 1];
        float w1 = dinv[s1] * dn, w2 = dinv[s2] * dn;
        acc = fmaf(xw[(size_t)s1 * HH + f], w1, acc);
        acc = fmaf(xw[(size_t)s2 * HH + f], w2, acc);
    }
    if (e < end) {
        int s1 = col[e];
        acc = fmaf(xw[(size_t)s1 * HH + f], dinv[s1] * dn, acc);
    }
    acc += b[f];
    out[(size_t)n * HH + f] = fmaxf(acc, 0.f);
}

// ---------------------------------------------------------------- conv + silu, transposed outputs
__global__ __launch_bounds__(256) void conv_silu_t(const float* __restrict__ xz,
                                                   const float* __restrict__ cw,
                                                   const float* __restrict__ cb,
                                                   float* __restrict__ xst,
                                                   float* __restrict__ szt) {
    __shared__ float tile[67][65];
    int tid = threadIdx.x;
    int t0 = blockIdx.x * 64;
    int c0 = blockIdx.y * 64;
#pragma unroll
    for (int l = 0; l < 17; l++) {
        int idx = tid + l * 256;
        if (idx < 67 * 64) {
            int r = idx >> 6, c = idx & 63;
            int gt = t0 - 3 + r;
            tile[r][c] = (gt >= 0) ? xz[(size_t)gt * 512 + c0 + c] : 0.f;
        }
    }
    __syncthreads();
    int tl = tid & 63;
    int d0 = tid >> 6;
    if (c0 < 256) {
#pragma unroll
        for (int l = 0; l < 16; l++) {
            int dl = d0 + l * 4;
            int dg = c0 + dl;
            float acc = cb[dg];
#pragma unroll
            for (int k = 0; k < DC; k++)
                acc = fmaf(tile[tl + k][dl], cw[dg * DC + k], acc);
            xst[dg * NN + t0 + tl] = siluf(acc);
        }
    } else {
#pragma unroll
        for (int l = 0; l < 16; l++) {
            int dl = d0 + l * 4;
            int dg = c0 - 256 + dl;
            szt[dg * NN + t0 + tl] = siluf(tile[tl + 3][dl]);
        }
    }
}

// ---------------------------------------------------------------- transpose dbl [NN][40] -> [40][NN]
__global__ __launch_bounds__(256) void transpose_dbl(const float* __restrict__ dbl,
                                                     float* __restrict__ dblt) {
    __shared__ float tile[64][41];
    int tid = threadIdx.x;
    int t0 = blockIdx.x * 64;
#pragma unroll
    for (int l = 0; l < 10; l++) {
        int idx = tid + l * 256;
        int r = idx / 40, c = idx - r * 40;
        tile[r][c] = dbl[(size_t)(t0 + r) * 40 + c];
    }
    __syncthreads();
#pragma unroll
    for (int l = 0; l < 10; l++) {
        int idx = tid + l * 256;
        int c = idx >> 6, t = idx & 63;
        dblt[c * NN + t0 + t] = tile[t][c];
    }
}

// ---------------------------------------------------------------- dt (transposed): DT_T[d][t]
__global__ __launch_bounds__(256) void dt_t_kernel(const float* __restrict__ dblt,
                                                   const float* __restrict__ W_dt,
                                                   const float* __restrict__ b_dt,
                                                   float* __restrict__ dtt) {
    int t = blockIdx.x * 256 + threadIdx.x;
    int d = blockIdx.y;
    float acc = b_dt[d];
#pragma unroll
    for (int j = 0; j < DTR; j++)
        acc = fmaf(dblt[j * NN + t], W_dt[j * DI + d], acc);
    dtt[d * NN + t] = softplusf(acc);
}

// ---------------------------------------------------------------- Mamba scan, 3 phases
// G=2: lane owns 2 states. sg = lane&7 (s = 2sg, 2sg+1), dl = lane>>3 (8 d per wave).
// Explicit 1-iteration register prefetch of all global streams.
__global__ __launch_bounds__(256) void scan_phase1(const float* __restrict__ dtt,
                                                   const float* __restrict__ xst,
                                                   const float* __restrict__ dblt,
                                                   const float* __restrict__ A_log,
                                                   float* __restrict__ chkP,
                                                   float* __restrict__ chkH) {
    int tid = threadIdx.x;
    int wave = tid >> 6, lane = tid & 63;
    int sg = lane & 7, dl = lane >> 3;
    int d = blockIdx.x * 32 + wave * 8 + dl;
    int chunk = blockIdx.y;
    int t0 = chunk * CHLEN;
    int s0 = 2 * sg;
    float A0 = -expf(A_log[d * DS + s0]);
    float A1 = -expf(A_log[d * DS + s0 + 1]);
    const float* dtp = dtt + d * NN + t0;
    const float* xsp = xst + d * NN + t0;
    const float* b0p = dblt + (8 + s0) * NN + t0;
    const float* b1p = dblt + (9 + s0) * NN + t0;
    float h0 = 0.f, h1 = 0.f, P0 = 1.f, P1 = 1.f;
    float4 d4 = *(const float4*)dtp;
    float4 x4 = *(const float4*)xsp;
    float4 b04 = *(const float4*)b0p;
    float4 b14 = *(const float4*)b1p;
    for (int i = 0; i < CHLEN; i += 4) {
        int ip = i + 4;
        float4 nd, nx, nb0, nb1;
        if (ip < CHLEN) {
            nd = *(const float4*)(dtp + ip);
            nx = *(const float4*)(xsp + ip);
            nb0 = *(const float4*)(b0p + ip);
            nb1 = *(const float4*)(b1p + ip);
        }
#define P1S(U) { float dtv = d4.U; float a0 = __expf(dtv * A0); float a1 = __expf(dtv * A1); \
        float dx = dtv * x4.U; h0 = fmaf(a0, h0, dx * b04.U); h1 = fmaf(a1, h1, dx * b14.U); \
        P0 *= a0; P1 *= a1; }
        P1S(x) P1S(y) P1S(z) P1S(w)
#undef P1S
        if (ip < CHLEN) { d4 = nd; x4 = nx; b04 = nb0; b14 = nb1; }
    }
    int idx = chunk * 4096 + d * DS + s0;
    float2 vP; vP.x = P0; vP.y = P1;
    float2 vH; vH.x = h0; vH.y = h1;
    *(float2*)(chkP + idx) = vP;
    *(float2*)(chkH + idx) = vH;
}

__global__ void scan_phase2(const float* __restrict__ chkP, const float* __restrict__ chkH,
                            float* __restrict__ init) {
    int idx = blockIdx.x * blockDim.x + threadIdx.x;  // 4096 total
    float h = 0.f;
    for (int c0 = 0; c0 < NCH; c0 += 8) {
        float p[8], q[8];
#pragma unroll
        for (int j = 0; j < 8; j++) {
            p[j] = chkP[(c0 + j) * 4096 + idx];
            q[j] = chkH[(c0 + j) * 4096 + idx];
        }
#pragma unroll
        for (int j = 0; j < 8; j++) {
            init[(c0 + j) * 4096 + idx] = h;
            h = fmaf(p[j], h, q[j]);
        }
    }
}

__global__ __launch_bounds__(256) void scan_phase3(const float* __restrict__ dtt,
                                                   const float* __restrict__ xst,
                                                   const float* __restrict__ dblt,
                                                   const float* __restrict__ A_log,
                                                   const float* __restrict__ init,
                                                   const float* __restrict__ D_p,
                                                   const float* __restrict__ szt,
                                                   float* __restrict__ y) {
    int tid = threadIdx.x;
    int wave = tid >> 6, lane = tid & 63;
    int sg = lane & 7, dl = lane >> 3;
    int d = blockIdx.x * 32 + wave * 8 + dl;
    int chunk = blockIdx.y;
    int t0 = chunk * CHLEN;
    int s0 = 2 * sg;
    float A0 = -expf(A_log[d * DS + s0]);
    float A1 = -expf(A_log[d * DS + s0 + 1]);
    float Dd = D_p[d];
    const float* dtp = dtt + d * NN + t0;
    const float* xsp = xst + d * NN + t0;
    const float* b0p = dblt + (8 + s0) * NN + t0;
    const float* b1p = dblt + (9 + s0) * NN + t0;
    const float* c0p = dblt + (24 + s0) * NN + t0;
    const float* c1p = dblt + (25 + s0) * NN + t0;
    const float* szp = szt + d * NN + t0;
    float* yout = y + (size_t)t0 * DI;
    float2 ini = *(const float2*)(init + chunk * 4096 + d * DS + s0);
    float h0 = ini.x, h1 = ini.y;
    float4 d4 = *(const float4*)dtp;
    float4 x4 = *(const float4*)xsp;
    float4 b04 = *(const float4*)b0p;
    float4 b14 = *(const float4*)b1p;
    float4 c04 = *(const float4*)c0p;
    float4 c14 = *(const float4*)c1p;
    float4 z4 = *(const float4*)szp;
    for (int i = 0; i < CHLEN; i += 4) {
        int ip = i + 4;
        float4 nd, nx, nb0, nb1, nc0, nc1, nz;
        if (ip < CHLEN) {
            nd = *(const float4*)(dtp + ip);
            nx = *(const float4*)(xsp + ip);
            nb0 = *(const float4*)(b0p + ip);
            nb1 = *(const float4*)(b1p + ip);
            nc0 = *(const float4*)(c0p + ip);
            nc1 = *(const float4*)(c1p + ip);
            nz = *(const float4*)(szp + ip);
        }
#define P3S(U) { float dtv = d4.U; float a0 = __expf(dtv * A0); float a1 = __expf(dtv * A1); \
        float dx = dtv * x4.U; h0 = fmaf(a0, h0, dx * b04.U); h1 = fmaf(a1, h1, dx * b14.U); \
        float c = fmaf(h1, c14.U, h0 * c04.U); \
        c += __shfl_xor(c, 1); c += __shfl_xor(c, 2); c += __shfl_xor(c, 4); \
        if (sg == 0) yout[d] = (c + Dd * x4.U) * z4.U; \
        yout += DI; }
        P3S(x) P3S(y) P3S(z) P3S(w)
#undef P3S
        if (ip < CHLEN) { d4 = nd; x4 = nx; b04 = nb0; b14 = nb1; c04 = nc0; c14 = nc1; z4 = nz; }
    }
}

// ---------------------------------------------------------------- add + LayerNorm (wave per row)
__global__ void add_ln(const float* __restrict__ hg, const float* __restrict__ hm,
                       const float* __restrict__ gamma, const float* __restrict__ beta,
                       float* __restrict__ out) {
    int row = blockIdx.x * 4 + (threadIdx.x >> 6);
    int lane = threadIdx.x & 63;
    size_t base = (size_t)row * HH;
    float v0 = hg[base + lane] + hm[base + lane];
    float v1 = hg[base + 64 + lane] + hm[base + 64 + lane];
    float sum = v0 + v1;
#pragma unroll
    for (int m = 32; m >= 1; m >>= 1) sum += __shfl_xor(sum, m);
    float mu = sum * (1.f / 128.f);
    float d0 = v0 - mu, d1 = v1 - mu;
    float vs = d0 * d0 + d1 * d1;
#pragma unroll
    for (int m = 32; m >= 1; m >>= 1) vs += __shfl_xor(vs, m);
    float inv = rsqrtf(vs * (1.f / 128.f) + 1e-5f);
    out[base + lane] = d0 * inv * gamma[lane] + beta[lane];
    out[base + 64 + lane] = d1 * inv * gamma[64 + lane] + beta[64 + lane];
}

// ---------------------------------------------------------------- pooling (batch sorted)
__global__ void pool_kernel(const float* __restrict__ hf, const int* __restrict__ batch,
                            float* __restrict__ ge, int* __restrict__ counts) {
    int f = threadIdx.x;  // 128
    int r0 = blockIdx.x * 128;
    int gcur = batch[r0];
    float acc = 0.f;
    int cnt = 0;
    for (int i = 0; i < 128; i++) {
        int r = r0 + i;
        int g = batch[r];
        if (g != gcur) {
            atomicAdd(&ge[gcur * HH + f], acc);
            if (f == 0) atomicAdd(&counts[gcur], cnt);
            acc = 0.f; cnt = 0; gcur = g;
        }
        acc += hf[(size_t)r * HH + f];
        cnt++;
    }
    atomicAdd(&ge[gcur * HH + f], acc);
    if (f == 0) atomicAdd(&counts[gcur], cnt);
}

__global__ void ge_norm(float* __restrict__ ge, const int* __restrict__ counts) {
    int idx = blockIdx.x * blockDim.x + threadIdx.x;
    if (idx < BB * HH) {
        int b = idx >> 7;
        ge[idx] /= fmaxf((float)counts[b], 1.f);
    }
}

// ---------------------------------------------------------------- output heads
__global__ void heads_kernel(const float* __restrict__ ge,
                             const float* Wc, const float* bc, const float* Wh, const float* bh,
                             const float* Wt, const float* bt, const float* Wp1, const float* bp1,
                             const float* Wp2, const float* bp2, const float* Wd, const float* bd,
                             const float* Ws, const float* bs, float* __restrict__ out) {
    int col = blockIdx.x * blockDim.x + threadIdx.x;
    int b = blockIdx.y;
    if (col >= OUTW) return;
    const float* W; const float* bi; int lc, w;
    if (col < 1)         { W = Wc;  bi = bc;  lc = col;        w = 1; }
    else if (col < 5)    { W = Wh;  bi = bh;  lc = col - 1;    w = 4; }
    else if (col < 8)    { W = Wt;  bi = bt;  lc = col - 5;    w = 3; }
    else if (col < 520)  { W = Wp1; bi = bp1; lc = col - 8;    w = 512; }
    else if (col < 1032) { W = Wp2; bi = bp2; lc = col - 520;  w = 512; }
    else if (col < 1544) { W = Wd;  bi = bd;  lc = col - 1032; w = 512; }
    else                 { W = Ws;  bi = bs;  lc = col - 1544; w = 8; }
    float acc = bi[lc];
#pragma unroll 8
    for (int f = 0; f < HH; f++) acc = fmaf(ge[b * HH + f], W[f * w + lc], acc);
    out[(size_t)b * OUTW + col] = acc;
}

// ---------------------------------------------------------------- launch
extern "C" void kernel_launch(void* const* d_in, const int* in_sizes, int n_in,
                              void* d_out, int out_size, void* d_ws, size_t ws_size,
                              hipStream_t stream) {
    const float* nf      = (const float*)d_in[0];
    const int*   ei      = (const int*)d_in[1];
    const int*   batch   = (const int*)d_in[2];
    const float* W_in    = (const float*)d_in[3];
    const float* b_in    = (const float*)d_in[4];
    const float* W_g1    = (const float*)d_in[5];
    const float* b_g1    = (const float*)d_in[6];
    const float* W_g2    = (const float*)d_in[7];
    const float* b_g2    = (const float*)d_in[8];
    const float* W_inproj= (const float*)d_in[9];
    const float* conv_w  = (const float*)d_in[10];
    const float* conv_b  = (const float*)d_in[11];
    const float* W_xproj = (const float*)d_in[12];
    const float* W_dt    = (const float*)d_in[13];
    const float* b_dt    = (const float*)d_in[14];
    const float* A_log   = (const float*)d_in[15];
    const float* D_p     = (const float*)d_in[16];
    const float* W_out   = (const float*)d_in[17];
    const float* gamma   = (const float*)d_in[18];
    const float* beta    = (const float*)d_in[19];
    const float* Wc = (const float*)d_in[20]; const float* bc = (const float*)d_in[21];
    const float* Wh = (const float*)d_in[22]; const float* bh = (const float*)d_in[23];
    const float* Wt = (const float*)d_in[24]; const float* bt = (const float*)d_in[25];
    const float* Wp1= (const float*)d_in[26]; const float* bp1= (const float*)d_in[27];
    const float* Wp2= (const float*)d_in[28]; const float* bp2= (const float*)d_in[29];
    const float* Wd = (const float*)d_in[30]; const float* bd = (const float*)d_in[31];
    const float* Ws = (const float*)d_in[32]; const float* bs = (const float*)d_in[33];

    const int* e_src = ei;
    const int* e_dst = ei + EE;

    // workspace layout (floats, then ints)
    float* w = (float*)d_ws;
    size_t o = 0;
    float* F0   = w + o; o += (size_t)NN * HH;
    float* F1   = w + o; o += (size_t)NN * HH;
    float* F2   = w + o; o += (size_t)NN * HH;
    float* XZ   = w + o; o += (size_t)NN * 512;  // dead after conv_silu_t; reused:
    float* DTT  = XZ;                             //   DT_T [DI][NN]
    float* Y    = XZ + (size_t)NN * DI;           //   y    [NN][DI]
    float* XST  = w + o; o += (size_t)NN * DI;   // x (conv+silu), transposed [DI][NN]
    float* SZT  = w + o; o += (size_t)NN * DI;   // silu(z), transposed [DI][NN]
    float* DBL  = w + o; o += (size_t)NN * 40;
    float* DBLT = w + o; o += (size_t)NN * 40;   // [40][NN]; rows 8..23 = B^T, 24..39 = C^T
    float* CHP  = w + o; o += (size_t)NCH * 4096;
    float* CHH  = w + o; o += (size_t)NCH * 4096;
    float* INI  = w + o; o += (size_t)NCH * 4096;
    float* GE   = w + o; o += BB * HH;
    float* DINV = w + o; o += NN;
    int* ip = (int*)(w + o);
    int* CNT    = ip; ip += NN;
    int* ROWPTR = ip; ip += NN + 1;
    int* CURSOR = ip; ip += NN;
    int* COL    = ip; ip += EE;
    int* COUNTS = ip; ip += BB;

    hipMemsetAsync(CNT, 0, NN * sizeof(int), stream);
    hipMemsetAsync(GE, 0, BB * HH * sizeof(float), stream);
    hipMemsetAsync(COUNTS, 0, BB * sizeof(int), stream);

    // CSR build
    deg_kernel<<<EE / 256, 256, 0, stream>>>(e_dst, CNT);
    prefix_kernel<<<1, 1024, 0, stream>>>(CNT, ROWPTR, CURSOR, DINV);
    scatter_kernel<<<EE / 256, 256, 0, stream>>>(e_src, e_dst, CURSOR, COL);

    // h0 = relu(nf @ W_in + b_in)
    gemm_k<<<dim3(2, NN / 64), 256, 0, stream>>>(nf, W_in, b_in, F0, NN, HH, FF, 1);
    // GCN layer 1
    gemm_k<<<dim3(2, NN / 64), 256, 0, stream>>>(F0, W_g1, nullptr, F1, NN, HH, HH, 0);
    gcn_gather<<<NN, HH, 0, stream>>>(F1, ROWPTR, COL, DINV, b_g1, F0);
    // GCN layer 2
    gemm_k<<<dim3(2, NN / 64), 256, 0, stream>>>(F0, W_g2, nullptr, F1, NN, HH, HH, 0);
    gcn_gather<<<NN, HH, 0, stream>>>(F1, ROWPTR, COL, DINV, b_g2, F2);  // F2 = h_gnn

    // xz = h_gnn @ W_inproj
    gemm_k<<<dim3(8, NN / 64), 256, 0, stream>>>(F2, W_inproj, nullptr, XZ, NN, 512, HH, 0);
    // conv + silu -> XST; silu(z) -> SZT (both transposed)
    conv_silu_t<<<dim3(NN / 64, 8), 256, 0, stream>>>(XZ, conv_w, conv_b, XST, SZT);
    // dbl = xs @ W_xproj (A^T layout)
    gemm_at<<<dim3(1, NN / 64), 256, 0, stream>>>(XST, W_xproj, DBL, NN, 40, DI);
    // transpose dbl -> DBLT
    transpose_dbl<<<NN / 64, 256, 0, stream>>>(DBL, DBLT);
    // dt (transposed) — overwrites XZ region (dead)
    dt_t_kernel<<<dim3(NN / 256, DI), 256, 0, stream>>>(DBLT, W_dt, b_dt, DTT);

    // Mamba scan
    scan_phase1<<<dim3(8, NCH), 256, 0, stream>>>(DTT, XST, DBLT, A_log, CHP, CHH);
    scan_phase2<<<16, 256, 0, stream>>>(CHP, CHH, INI);
    scan_phase3<<<dim3(8, NCH), 256, 0, stream>>>(DTT, XST, DBLT, A_log, INI, D_p, SZT, Y);

    // h_mamba = y @ W_out -> F1
    gemm_k<<<dim3(2, NN / 64), 256, 0, stream>>>(Y, W_out, nullptr, F1, NN, HH, DI, 0);
    // hh = h_gnn + h_mamba; LayerNorm -> F0
    add_ln<<<NN / 4, 256, 0, stream>>>(F2, F1, gamma, beta, F0);

    // pooling
    pool_kernel<<<NN / 128, HH, 0, stream>>>(F0, batch, GE, COUNTS);
    ge_norm<<<(BB * HH + 255) / 256, 256, 0, stream>>>(GE, COUNTS);

    // heads
    heads_kernel<<<dim3((OUTW + 127) / 128, BB), 128, 0, stream>>>(
        GE, Wc, bc, Wh, bh, Wt, bt, Wp1, bp1, Wp2, bp2, Wd, bd, Ws, bs, (float*)d_out);
}

// Round 4
// 507.167 us; speedup vs baseline: 1.2211x; 1.0531x over previous
//
#include <hip/hip_runtime.h>
#include <math.h>

#define NN 16384
#define EE 262144
#define FF 32
#define HH 128
#define BB 16
#define DI 256
#define DS 16
#define DC 4
#define DTR 8
#define OUTW 1552
#define NCH 256
#define CHLEN 64    // NCH*CHLEN == NN
#define NG 8        // phase2 groups
#define GL 32       // chunks per group; NG*GL == NCH

// ---------------------------------------------------------------- utilities
__device__ __forceinline__ float siluf(float v) { return v / (1.f + __expf(-v)); }
__device__ __forceinline__ float softplusf(float v) {
    return fmaxf(v, 0.f) + log1pf(expf(-fabsf(v)));
}

// ---------------------------------------------------------------- CSR build
__global__ void deg_kernel(const int* __restrict__ dst, int* __restrict__ cnt) {
    int e = blockIdx.x * blockDim.x + threadIdx.x;
    if (e < EE) atomicAdd(&cnt[dst[e]], 1);
}

__global__ __launch_bounds__(1024) void prefix_kernel(const int* __restrict__ cnt,
                                                      int* __restrict__ rowptr,
                                                      int* __restrict__ cursor,
                                                      float* __restrict__ dinv) {
    __shared__ int part[1024];
    int tid = threadIdx.x;
    int4 c4[4];
#pragma unroll
    for (int j = 0; j < 4; j++) c4[j] = ((const int4*)cnt)[tid * 4 + j];
    int v[16] = {c4[0].x, c4[0].y, c4[0].z, c4[0].w, c4[1].x, c4[1].y, c4[1].z, c4[1].w,
                 c4[2].x, c4[2].y, c4[2].z, c4[2].w, c4[3].x, c4[3].y, c4[3].z, c4[3].w};
    int s = 0;
#pragma unroll
    for (int j = 0; j < 16; j++) s += v[j];
    part[tid] = s;
    __syncthreads();
    for (int off = 1; off < 1024; off <<= 1) {
        int t = (tid >= off) ? part[tid - off] : 0;
        __syncthreads();
        part[tid] += t;
        __syncthreads();
    }
    int running = part[tid] - s;
    int rp[16];
    float dv[16];
#pragma unroll
    for (int j = 0; j < 16; j++) {
        rp[j] = running;
        running += v[j];
        dv[j] = rsqrtf((float)(v[j] + 1));  // +1 self loop
    }
#pragma unroll
    for (int j = 0; j < 4; j++) {
        int4 r4; r4.x = rp[j*4]; r4.y = rp[j*4+1]; r4.z = rp[j*4+2]; r4.w = rp[j*4+3];
        ((int4*)rowptr)[tid * 4 + j] = r4;
        ((int4*)cursor)[tid * 4 + j] = r4;
        float4 d4; d4.x = dv[j*4]; d4.y = dv[j*4+1]; d4.z = dv[j*4+2]; d4.w = dv[j*4+3];
        ((float4*)dinv)[tid * 4 + j] = d4;
    }
    if (tid == 1023) rowptr[NN] = part[1023];
}

__global__ void scatter_kernel(const int* __restrict__ src, const int* __restrict__ dst,
                               int* __restrict__ cursor, int* __restrict__ col) {
    int e = blockIdx.x * blockDim.x + threadIdx.x;
    if (e < EE) {
        int d = dst[e];
        int pos = atomicAdd(&cursor[d], 1);
        col[pos] = src[e];
    }
}

// ---------------------------------------------------------------- GEMM (fp32, 64x64 tile)
__global__ __launch_bounds__(256) void gemm_k(const float* __restrict__ A,
                                              const float* __restrict__ B,
                                              const float* __restrict__ bias,
                                              float* __restrict__ C,
                                              int M, int Nn, int K, int act) {
    __shared__ float As[16][68];
    __shared__ float Bs[16][68];
    int tid = threadIdx.x;
    int m0 = blockIdx.y * 64;
    int n0 = blockIdx.x * 64;
    int ty = tid >> 4, tx = tid & 15;
    float acc[4][4] = {{0.f}};
    for (int k0 = 0; k0 < K; k0 += 16) {
#pragma unroll
        for (int l = 0; l < 4; l++) {
            int idx = tid + l * 256;
            int i = idx >> 4, j = idx & 15;
            As[j][i] = A[(size_t)(m0 + i) * K + k0 + j];
        }
#pragma unroll
        for (int l = 0; l < 4; l++) {
            int idx = tid + l * 256;
            int i = idx >> 6, j = idx & 63;
            int n = n0 + j;
            Bs[i][j] = (n < Nn) ? B[(size_t)(k0 + i) * Nn + n] : 0.f;
        }
        __syncthreads();
#pragma unroll
        for (int kk = 0; kk < 16; kk++) {
            float4 a4 = *(const float4*)&As[kk][ty * 4];
            float4 b4 = *(const float4*)&Bs[kk][tx * 4];
            float av[4] = {a4.x, a4.y, a4.z, a4.w};
            float bv[4] = {b4.x, b4.y, b4.z, b4.w};
#pragma unroll
            for (int r = 0; r < 4; r++)
#pragma unroll
                for (int c = 0; c < 4; c++) acc[r][c] = fmaf(av[r], bv[c], acc[r][c]);
        }
        __syncthreads();
    }
    int nb = n0 + tx * 4;
    if (nb < Nn) {
        float4 bi4 = {0.f, 0.f, 0.f, 0.f};
        if (bias) bi4 = *(const float4*)&bias[nb];
#pragma unroll
        for (int r = 0; r < 4; r++) {
            int m = m0 + ty * 4 + r;
            float4 v;
            v.x = acc[r][0] + bi4.x; v.y = acc[r][1] + bi4.y;
            v.z = acc[r][2] + bi4.z; v.w = acc[r][3] + bi4.w;
            if (act == 1) {
                v.x = fmaxf(v.x, 0.f); v.y = fmaxf(v.y, 0.f);
                v.z = fmaxf(v.z, 0.f); v.w = fmaxf(v.w, 0.f);
            }
            *(float4*)&C[(size_t)m * Nn + nb] = v;
        }
    }
}

// ---------------------------------------------------------------- GEMM with A^T input (A stored [K][M])
__global__ __launch_bounds__(256) void gemm_at(const float* __restrict__ AT,
                                               const float* __restrict__ B,
                                               float* __restrict__ C,
                                               int M, int Nn, int K) {
    __shared__ float As[16][68];
    __shared__ float Bs[16][68];
    int tid = threadIdx.x;
    int m0 = blockIdx.y * 64;
    int n0 = blockIdx.x * 64;
    int ty = tid >> 4, tx = tid & 15;
    float acc[4][4] = {{0.f}};
    for (int k0 = 0; k0 < K; k0 += 16) {
#pragma unroll
        for (int l = 0; l < 4; l++) {
            int idx = tid + l * 256;
            int kk = idx >> 6, i = idx & 63;
            As[kk][i] = AT[(size_t)(k0 + kk) * M + m0 + i];
        }
#pragma unroll
        for (int l = 0; l < 4; l++) {
            int idx = tid + l * 256;
            int i = idx >> 6, j = idx & 63;
            int n = n0 + j;
            Bs[i][j] = (n < Nn) ? B[(size_t)(k0 + i) * Nn + n] : 0.f;
        }
        __syncthreads();
#pragma unroll
        for (int kk = 0; kk < 16; kk++) {
            float4 a4 = *(const float4*)&As[kk][ty * 4];
            float4 b4 = *(const float4*)&Bs[kk][tx * 4];
            float av[4] = {a4.x, a4.y, a4.z, a4.w};
            float bv[4] = {b4.x, b4.y, b4.z, b4.w};
#pragma unroll
            for (int r = 0; r < 4; r++)
#pragma unroll
                for (int c = 0; c < 4; c++) acc[r][c] = fmaf(av[r], bv[c], acc[r][c]);
        }
        __syncthreads();
    }
    int nb = n0 + tx * 4;
    if (nb < Nn) {
#pragma unroll
        for (int r = 0; r < 4; r++) {
            int m = m0 + ty * 4 + r;
            float4 v;
            v.x = acc[r][0]; v.y = acc[r][1]; v.z = acc[r][2]; v.w = acc[r][3];
            *(float4*)&C[(size_t)m * Nn + nb] = v;
        }
    }
}

// ---------------------------------------------------------------- GCN gather (CSR by dest), 4-deep edge unroll
__global__ void gcn_gather(const float* __restrict__ xw, const int* __restrict__ rowptr,
                           const int* __restrict__ col, const float* __restrict__ dinv,
                           const float* __restrict__ b, float* __restrict__ out) {
    int n = blockIdx.x;
    int f = threadIdx.x;  // 128
    float dn = dinv[n];
    float acc = xw[(size_t)n * HH + f] * dn * dn;  // self loop
    int beg = rowptr[n], end = rowptr[n + 1];
    int e = beg;
    for (; e + 4 <= end; e += 4) {
        int s0 = col[e], s1 = col[e + 1], s2 = col[e + 2], s3 = col[e + 3];
        float w0 = dinv[s0] * dn, w1 = dinv[s1] * dn, w2 = dinv[s2] * dn, w3 = dinv[s3] * dn;
        float v0 = xw[(size_t)s0 * HH + f];
        float v1 = xw[(size_t)s1 * HH + f];
        float v2 = xw[(size_t)s2 * HH + f];
        float v3 = xw[(size_t)s3 * HH + f];
        acc = fmaf(v0, w0, acc);
        acc = fmaf(v1, w1, acc);
        acc = fmaf(v2, w2, acc);
        acc = fmaf(v3, w3, acc);
    }
    for (; e < end; e++) {
        int s0 = col[e];
        acc = fmaf(xw[(size_t)s0 * HH + f], dinv[s0] * dn, acc);
    }
    acc += b[f];
    out[(size_t)n * HH + f] = fmaxf(acc, 0.f);
}

// ---------------------------------------------------------------- conv + silu, transposed outputs
__global__ __launch_bounds__(256) void conv_silu_t(const float* __restrict__ xz,
                                                   const float* __restrict__ cw,
                                                   const float* __restrict__ cb,
                                                   float* __restrict__ xst,
                                                   float* __restrict__ szt) {
    __shared__ float tile[67][65];
    int tid = threadIdx.x;
    int t0 = blockIdx.x * 64;
    int c0 = blockIdx.y * 64;
#pragma unroll
    for (int l = 0; l < 17; l++) {
        int idx = tid + l * 256;
        if (idx < 67 * 64) {
            int r = idx >> 6, c = idx & 63;
            int gt = t0 - 3 + r;
            tile[r][c] = (gt >= 0) ? xz[(size_t)gt * 512 + c0 + c] : 0.f;
        }
    }
    __syncthreads();
    int tl = tid & 63;
    int d0 = tid >> 6;
    if (c0 < 256) {
#pragma unroll
        for (int l = 0; l < 16; l++) {
            int dl = d0 + l * 4;
            int dg = c0 + dl;
            float acc = cb[dg];
#pragma unroll
            for (int k = 0; k < DC; k++)
                acc = fmaf(tile[tl + k][dl], cw[dg * DC + k], acc);
            xst[dg * NN + t0 + tl] = siluf(acc);
        }
    } else {
#pragma unroll
        for (int l = 0; l < 16; l++) {
            int dl = d0 + l * 4;
            int dg = c0 - 256 + dl;
            szt[dg * NN + t0 + tl] = siluf(tile[tl + 3][dl]);
        }
    }
}

// ---------------------------------------------------------------- transpose dbl [NN][40] -> [40][NN]
__global__ __launch_bounds__(256) void transpose_dbl(const float* __restrict__ dbl,
                                                     float* __restrict__ dblt) {
    __shared__ float tile[64][41];
    int tid = threadIdx.x;
    int t0 = blockIdx.x * 64;
#pragma unroll
    for (int l = 0; l < 10; l++) {
        int idx = tid + l * 256;
        int r = idx / 40, c = idx - r * 40;
        tile[r][c] = dbl[(size_t)(t0 + r) * 40 + c];
    }
    __syncthreads();
#pragma unroll
    for (int l = 0; l < 10; l++) {
        int idx = tid + l * 256;
        int c = idx >> 6, t = idx & 63;
        dblt[c * NN + t0 + t] = tile[t][c];
    }
}

// ---------------------------------------------------------------- dt (transposed): DT_T[d][t]
__global__ __launch_bounds__(256) void dt_t_kernel(const float* __restrict__ dblt,
                                                   const float* __restrict__ W_dt,
                                                   const float* __restrict__ b_dt,
                                                   float* __restrict__ dtt) {
    int t = blockIdx.x * 256 + threadIdx.x;
    int d = blockIdx.y;
    float acc = b_dt[d];
#pragma unroll
    for (int j = 0; j < DTR; j++)
        acc = fmaf(dblt[j * NN + t], W_dt[j * DI + d], acc);
    dtt[d * NN + t] = softplusf(acc);
}

// ---------------------------------------------------------------- Mamba scan
// G=2: sg = lane&7 (s = 2sg, 2sg+1), dl = lane>>3. Block covers 32 d; grid (8, NCH).
// Depth-2 register prefetch on cold d-major streams; B/C rows are block-shared (L1-warm).
__global__ __launch_bounds__(256) void scan_phase1(const float* __restrict__ dtt,
                                                   const float* __restrict__ xst,
                                                   const float* __restrict__ dblt,
                                                   const float* __restrict__ A_log,
                                                   float* __restrict__ chkP,
                                                   float* __restrict__ chkH) {
    int tid = threadIdx.x;
    int wave = tid >> 6, lane = tid & 63;
    int sg = lane & 7, dl = lane >> 3;
    int d = blockIdx.x * 32 + wave * 8 + dl;
    int chunk = blockIdx.y;
    int t0 = chunk * CHLEN;
    int s0 = 2 * sg;
    float A0 = -expf(A_log[d * DS + s0]);
    float A1 = -expf(A_log[d * DS + s0 + 1]);
    const float* dtp = dtt + d * NN + t0;
    const float* xsp = xst + d * NN + t0;
    const float* b0p = dblt + (8 + s0) * NN + t0;
    const float* b1p = dblt + (9 + s0) * NN + t0;
    float h0 = 0.f, h1 = 0.f, P0 = 1.f, P1 = 1.f;
    float4 dA = *(const float4*)dtp;
    float4 xA = *(const float4*)xsp;
    float4 dB = *(const float4*)(dtp + 4);
    float4 xB = *(const float4*)(xsp + 4);
    for (int i = 0; i < CHLEN; i += 4) {
        float4 dC, xC;
        if (i + 8 < CHLEN) {
            dC = *(const float4*)(dtp + i + 8);
            xC = *(const float4*)(xsp + i + 8);
        }
        float4 b04 = *(const float4*)(b0p + i);
        float4 b14 = *(const float4*)(b1p + i);
#define P1S(U) { float dtv = dA.U; float a0 = __expf(dtv * A0); float a1 = __expf(dtv * A1); \
        float dx = dtv * xA.U; h0 = fmaf(a0, h0, dx * b04.U); h1 = fmaf(a1, h1, dx * b14.U); \
        P0 *= a0; P1 *= a1; }
        P1S(x) P1S(y) P1S(z) P1S(w)
#undef P1S
        dA = dB; xA = xB; dB = dC; xB = xC;
    }
    int idx = chunk * 4096 + d * DS + s0;
    float2 vP; vP.x = P0; vP.y = P1;
    float2 vH; vH.x = h0; vH.y = h1;
    *(float2*)(chkP + idx) = vP;
    *(float2*)(chkH + idx) = vH;
}

// phase2a: compose chunks within each group of GL -> (GP, GH) per (group, idx)
__global__ void scan_phase2a(const float* __restrict__ chkP, const float* __restrict__ chkH,
                             float* __restrict__ gp, float* __restrict__ gh) {
    int g = blockIdx.x * blockDim.x + threadIdx.x;  // 4096*NG
    int idx = g & 4095;
    int grp = g >> 12;
    int c0 = grp * GL;
    float P = 1.f, H = 0.f;
    for (int j = 0; j < GL; j += 4) {
        float p[4], q[4];
#pragma unroll
        for (int jj = 0; jj < 4; jj++) {
            p[jj] = chkP[(c0 + j + jj) * 4096 + idx];
            q[jj] = chkH[(c0 + j + jj) * 4096 + idx];
        }
#pragma unroll
        for (int jj = 0; jj < 4; jj++) {
            H = fmaf(p[jj], H, q[jj]);
            P *= p[jj];
        }
    }
    gp[grp * 4096 + idx] = P;
    gh[grp * 4096 + idx] = H;
}

// phase2b: scan across the NG groups -> group-initial states
__global__ void scan_phase2b(const float* __restrict__ gp, const float* __restrict__ gh,
                             float* __restrict__ gini) {
    int idx = blockIdx.x * blockDim.x + threadIdx.x;  // 4096
    float h = 0.f;
#pragma unroll
    for (int g = 0; g < NG; g++) {
        gini[g * 4096 + idx] = h;
        h = fmaf(gp[g * 4096 + idx], h, gh[g * 4096 + idx]);
    }
}

// phase2c: replay within group, writing per-chunk initial states
__global__ void scan_phase2c(const float* __restrict__ chkP, const float* __restrict__ chkH,
                             const float* __restrict__ gini, float* __restrict__ init) {
    int g = blockIdx.x * blockDim.x + threadIdx.x;
    int idx = g & 4095;
    int grp = g >> 12;
    int c0 = grp * GL;
    float h = gini[grp * 4096 + idx];
    for (int j = 0; j < GL; j += 4) {
        float p[4], q[4];
#pragma unroll
        for (int jj = 0; jj < 4; jj++) {
            p[jj] = chkP[(c0 + j + jj) * 4096 + idx];
            q[jj] = chkH[(c0 + j + jj) * 4096 + idx];
        }
#pragma unroll
        for (int jj = 0; jj < 4; jj++) {
            init[(c0 + j + jj) * 4096 + idx] = h;
            h = fmaf(p[jj], h, q[jj]);
        }
    }
}

__global__ __launch_bounds__(256) void scan_phase3(const float* __restrict__ dtt,
                                                   const float* __restrict__ xst,
                                                   const float* __restrict__ dblt,
                                                   const float* __restrict__ A_log,
                                                   const float* __restrict__ init,
                                                   const float* __restrict__ D_p,
                                                   const float* __restrict__ szt,
                                                   float* __restrict__ yt) {
    int tid = threadIdx.x;
    int wave = tid >> 6, lane = tid & 63;
    int sg = lane & 7, dl = lane >> 3;
    int d = blockIdx.x * 32 + wave * 8 + dl;
    int chunk = blockIdx.y;
    int t0 = chunk * CHLEN;
    int s0 = 2 * sg;
    float A0 = -expf(A_log[d * DS + s0]);
    float A1 = -expf(A_log[d * DS + s0 + 1]);
    float Dd = D_p[d];
    const float* dtp = dtt + d * NN + t0;
    const float* xsp = xst + d * NN + t0;
    const float* szp = szt + d * NN + t0;
    const float* b0p = dblt + (8 + s0) * NN + t0;
    const float* b1p = dblt + (9 + s0) * NN + t0;
    const float* c0p = dblt + (24 + s0) * NN + t0;
    const float* c1p = dblt + (25 + s0) * NN + t0;
    float* ytp = yt + d * NN + t0;
    float2 ini = *(const float2*)(init + chunk * 4096 + d * DS + s0);
    float h0 = ini.x, h1 = ini.y;
    float4 dA = *(const float4*)dtp;
    float4 xA = *(const float4*)xsp;
    float4 zA = *(const float4*)szp;
    float4 dB = *(const float4*)(dtp + 4);
    float4 xB = *(const float4*)(xsp + 4);
    float4 zB = *(const float4*)(szp + 4);
    for (int i = 0; i < CHLEN; i += 4) {
        float4 dC, xC, zC;
        if (i + 8 < CHLEN) {
            dC = *(const float4*)(dtp + i + 8);
            xC = *(const float4*)(xsp + i + 8);
            zC = *(const float4*)(szp + i + 8);
        }
        float4 b04 = *(const float4*)(b0p + i);
        float4 b14 = *(const float4*)(b1p + i);
        float4 c04 = *(const float4*)(c0p + i);
        float4 c14 = *(const float4*)(c1p + i);
        float4 yv;
#define P3S(U) { float dtv = dA.U; float a0 = __expf(dtv * A0); float a1 = __expf(dtv * A1); \
        float dx = dtv * xA.U; h0 = fmaf(a0, h0, dx * b04.U); h1 = fmaf(a1, h1, dx * b14.U); \
        float c = fmaf(h1, c14.U, h0 * c04.U); \
        c += __shfl_xor(c, 1); c += __shfl_xor(c, 2); c += __shfl_xor(c, 4); \
        yv.U = (c + Dd * xA.U) * zA.U; }
        P3S(x) P3S(y) P3S(z) P3S(w)
#undef P3S
        if (sg == 0) *(float4*)(ytp + i) = yv;
        dA = dB; xA = xB; zA = zB; dB = dC; xB = xC; zB = zC;
    }
}

// ---------------------------------------------------------------- add + LayerNorm (wave per row)
__global__ void add_ln(const float* __restrict__ hg, const float* __restrict__ hm,
                       const float* __restrict__ gamma, const float* __restrict__ beta,
                       float* __restrict__ out) {
    int row = blockIdx.x * 4 + (threadIdx.x >> 6);
    int lane = threadIdx.x & 63;
    size_t base = (size_t)row * HH;
    float v0 = hg[base + lane] + hm[base + lane];
    float v1 = hg[base + 64 + lane] + hm[base + 64 + lane];
    float sum = v0 + v1;
#pragma unroll
    for (int m = 32; m >= 1; m >>= 1) sum += __shfl_xor(sum, m);
    float mu = sum * (1.f / 128.f);
    float d0 = v0 - mu, d1 = v1 - mu;
    float vs = d0 * d0 + d1 * d1;
#pragma unroll
    for (int m = 32; m >= 1; m >>= 1) vs += __shfl_xor(vs, m);
    float inv = rsqrtf(vs * (1.f / 128.f) + 1e-5f);
    out[base + lane] = d0 * inv * gamma[lane] + beta[lane];
    out[base + 64 + lane] = d1 * inv * gamma[64 + lane] + beta[64 + lane];
}

// ---------------------------------------------------------------- pooling (batch sorted), 4-row unroll
__global__ void pool_kernel(const float* __restrict__ hf, const int* __restrict__ batch,
                            float* __restrict__ ge, int* __restrict__ counts) {
    int f = threadIdx.x;  // 128
    int r0 = blockIdx.x * 128;
    int gcur = batch[r0];
    float acc = 0.f;
    int cnt = 0;
    for (int i = 0; i < 128; i += 4) {
        int r = r0 + i;
        int g0 = batch[r], g3 = batch[r + 3];
        float v0 = hf[(size_t)r * HH + f];
        float v1 = hf[(size_t)(r + 1) * HH + f];
        float v2 = hf[(size_t)(r + 2) * HH + f];
        float v3 = hf[(size_t)(r + 3) * HH + f];
        if (g0 == gcur && g3 == gcur) {  // sorted => all four in gcur
            acc += (v0 + v1) + (v2 + v3);
            cnt += 4;
        } else {
            int gs[4] = {g0, batch[r + 1], batch[r + 2], g3};
            float vs[4] = {v0, v1, v2, v3};
#pragma unroll
            for (int k = 0; k < 4; k++) {
                if (gs[k] != gcur) {
                    atomicAdd(&ge[gcur * HH + f], acc);
                    if (f == 0) atomicAdd(&counts[gcur], cnt);
                    acc = 0.f; cnt = 0; gcur = gs[k];
                }
                acc += vs[k];
                cnt++;
            }
        }
    }
    atomicAdd(&ge[gcur * HH + f], acc);
    if (f == 0) atomicAdd(&counts[gcur], cnt);
}

__global__ void ge_norm(float* __restrict__ ge, const int* __restrict__ counts) {
    int idx = blockIdx.x * blockDim.x + threadIdx.x;
    if (idx < BB * HH) {
        int b = idx >> 7;
        ge[idx] /= fmaxf((float)counts[b], 1.f);
    }
}

// ---------------------------------------------------------------- output heads
__global__ void heads_kernel(const float* __restrict__ ge,
                             const float* Wc, const float* bc, const float* Wh, const float* bh,
                             const float* Wt, const float* bt, const float* Wp1, const float* bp1,
                             const float* Wp2, const float* bp2, const float* Wd, const float* bd,
                             const float* Ws, const float* bs, float* __restrict__ out) {
    int col = blockIdx.x * blockDim.x + threadIdx.x;
    int b = blockIdx.y;
    if (col >= OUTW) return;
    const float* W; const float* bi; int lc, w;
    if (col < 1)         { W = Wc;  bi = bc;  lc = col;        w = 1; }
    else if (col < 5)    { W = Wh;  bi = bh;  lc = col - 1;    w = 4; }
    else if (col < 8)    { W = Wt;  bi = bt;  lc = col - 5;    w = 3; }
    else if (col < 520)  { W = Wp1; bi = bp1; lc = col - 8;    w = 512; }
    else if (col < 1032) { W = Wp2; bi = bp2; lc = col - 520;  w = 512; }
    else if (col < 1544) { W = Wd;  bi = bd;  lc = col - 1032; w = 512; }
    else                 { W = Ws;  bi = bs;  lc = col - 1544; w = 8; }
    float acc = bi[lc];
#pragma unroll 8
    for (int f = 0; f < HH; f++) acc = fmaf(ge[b * HH + f], W[f * w + lc], acc);
    out[(size_t)b * OUTW + col] = acc;
}

// ---------------------------------------------------------------- launch
extern "C" void kernel_launch(void* const* d_in, const int* in_sizes, int n_in,
                              void* d_out, int out_size, void* d_ws, size_t ws_size,
                              hipStream_t stream) {
    const float* nf      = (const float*)d_in[0];
    const int*   ei      = (const int*)d_in[1];
    const int*   batch   = (const int*)d_in[2];
    const float* W_in    = (const float*)d_in[3];
    const float* b_in    = (const float*)d_in[4];
    const float* W_g1    = (const float*)d_in[5];
    const float* b_g1    = (const float*)d_in[6];
    const float* W_g2    = (const float*)d_in[7];
    const float* b_g2    = (const float*)d_in[8];
    const float* W_inproj= (const float*)d_in[9];
    const float* conv_w  = (const float*)d_in[10];
    const float* conv_b  = (const float*)d_in[11];
    const float* W_xproj = (const float*)d_in[12];
    const float* W_dt    = (const float*)d_in[13];
    const float* b_dt    = (const float*)d_in[14];
    const float* A_log   = (const float*)d_in[15];
    const float* D_p     = (const float*)d_in[16];
    const float* W_out   = (const float*)d_in[17];
    const float* gamma   = (const float*)d_in[18];
    const float* beta    = (const float*)d_in[19];
    const float* Wc = (const float*)d_in[20]; const float* bc = (const float*)d_in[21];
    const float* Wh = (const float*)d_in[22]; const float* bh = (const float*)d_in[23];
    const float* Wt = (const float*)d_in[24]; const float* bt = (const float*)d_in[25];
    const float* Wp1= (const float*)d_in[26]; const float* bp1= (const float*)d_in[27];
    const float* Wp2= (const float*)d_in[28]; const float* bp2= (const float*)d_in[29];
    const float* Wd = (const float*)d_in[30]; const float* bd = (const float*)d_in[31];
    const float* Ws = (const float*)d_in[32]; const float* bs = (const float*)d_in[33];

    const int* e_src = ei;
    const int* e_dst = ei + EE;

    // workspace layout (floats, then ints)
    float* w = (float*)d_ws;
    size_t o = 0;
    float* F0   = w + o; o += (size_t)NN * HH;   // 2M floats; dead during scan -> CHP/CHH
    float* F1   = w + o; o += (size_t)NN * HH;   // dead during scan -> INI
    float* F2   = w + o; o += (size_t)NN * HH;
    float* XZ   = w + o; o += (size_t)NN * 512;  // dead after conv_silu_t; reused:
    float* DTT  = XZ;                             //   DT_T [DI][NN]
    float* YT   = XZ + (size_t)NN * DI;           //   y^T  [DI][NN]
    float* XST  = w + o; o += (size_t)NN * DI;   // x (conv+silu), transposed [DI][NN]
    float* SZT  = w + o; o += (size_t)NN * DI;   // silu(z), transposed [DI][NN]
    float* DBL  = w + o; o += (size_t)NN * 40;   // dead after transpose_dbl -> GP/GH/GINI
    float* DBLT = w + o; o += (size_t)NN * 40;   // [40][NN]; rows 8..23 = B^T, 24..39 = C^T
    float* GE   = w + o; o += BB * HH;
    float* DINV = w + o; o += NN;
    int* ip = (int*)(w + o);
    int* CNT    = ip; ip += NN;
    int* ROWPTR = ip; ip += NN + 1;
    int* CURSOR = ip; ip += NN;
    int* COL    = ip; ip += EE;
    int* COUNTS = ip; ip += BB;

    // overlays (regions dead during the scan)
    float* CHP  = F0;                         // NCH*4096 = 1M floats
    float* CHH  = F0 + (size_t)NCH * 4096;    // 1M floats (F0 holds 2M)
    float* INI  = F1;                         // NCH*4096 = 1M floats (F1 holds 2M)
    float* GP   = DBL;                        // NG*4096
    float* GH   = DBL + NG * 4096;
    float* GINI = DBL + 2 * NG * 4096;

    hipMemsetAsync(CNT, 0, NN * sizeof(int), stream);
    hipMemsetAsync(GE, 0, BB * HH * sizeof(float), stream);
    hipMemsetAsync(COUNTS, 0, BB * sizeof(int), stream);

    // CSR build
    deg_kernel<<<EE / 256, 256, 0, stream>>>(e_dst, CNT);
    prefix_kernel<<<1, 1024, 0, stream>>>(CNT, ROWPTR, CURSOR, DINV);
    scatter_kernel<<<EE / 256, 256, 0, stream>>>(e_src, e_dst, CURSOR, COL);

    // h0 = relu(nf @ W_in + b_in)
    gemm_k<<<dim3(2, NN / 64), 256, 0, stream>>>(nf, W_in, b_in, F0, NN, HH, FF, 1);
    // GCN layer 1
    gemm_k<<<dim3(2, NN / 64), 256, 0, stream>>>(F0, W_g1, nullptr, F1, NN, HH, HH, 0);
    gcn_gather<<<NN, HH, 0, stream>>>(F1, ROWPTR, COL, DINV, b_g1, F0);
    // GCN layer 2
    gemm_k<<<dim3(2, NN / 64), 256, 0, stream>>>(F0, W_g2, nullptr, F1, NN, HH, HH, 0);
    gcn_gather<<<NN, HH, 0, stream>>>(F1, ROWPTR, COL, DINV, b_g2, F2);  // F2 = h_gnn

    // xz = h_gnn @ W_inproj
    gemm_k<<<dim3(8, NN / 64), 256, 0, stream>>>(F2, W_inproj, nullptr, XZ, NN, 512, HH, 0);
    // conv + silu -> XST; silu(z) -> SZT (both transposed)
    conv_silu_t<<<dim3(NN / 64, 8), 256, 0, stream>>>(XZ, conv_w, conv_b, XST, SZT);
    // dbl = xs @ W_xproj (A^T layout)
    gemm_at<<<dim3(1, NN / 64), 256, 0, stream>>>(XST, W_xproj, DBL, NN, 40, DI);
    // transpose dbl -> DBLT
    transpose_dbl<<<NN / 64, 256, 0, stream>>>(DBL, DBLT);
    // dt (transposed) — overwrites XZ region (dead)
    dt_t_kernel<<<dim3(NN / 256, DI), 256, 0, stream>>>(DBLT, W_dt, b_dt, DTT);

    // Mamba scan
    scan_phase1<<<dim3(8, NCH), 256, 0, stream>>>(DTT, XST, DBLT, A_log, CHP, CHH);
    scan_phase2a<<<(4096 * NG) / 256, 256, 0, stream>>>(CHP, CHH, GP, GH);
    scan_phase2b<<<16, 256, 0, stream>>>(GP, GH, GINI);
    scan_phase2c<<<(4096 * NG) / 256, 256, 0, stream>>>(CHP, CHH, GINI, INI);
    scan_phase3<<<dim3(8, NCH), 256, 0, stream>>>(DTT, XST, DBLT, A_log, INI, D_p, SZT, YT);

    // h_mamba = y @ W_out -> F1 (y stored transposed)
    gemm_at<<<dim3(2, NN / 64), 256, 0, stream>>>(YT, W_out, F1, NN, HH, DI);
    // hh = h_gnn + h_mamba; LayerNorm -> F0
    add_ln<<<NN / 4, 256, 0, stream>>>(F2, F1, gamma, beta, F0);

    // pooling
    pool_kernel<<<NN / 128, HH, 0, stream>>>(F0, batch, GE, COUNTS);
    ge_norm<<<(BB * HH + 255) / 256, 256, 0, stream>>>(GE, COUNTS);

    // heads
    heads_kernel<<<dim3((OUTW + 127) / 128, BB), 128, 0, stream>>>(
        GE, Wc, bc, Wh, bh, Wt, bt, Wp1, bp1, Wp2, bp2, Wd, bd, Ws, bs, (float*)d_out);
}